// Round 15
// baseline (1524.521 us; speedup 1.0000x reference)
//
#include <hip/hip_runtime.h>
#include <hip/hip_bf16.h>
#include <math.h>

// PAFM fused v9: v8 schedule split into TWO independent barrier domains per CU:
// 256-thr blocks (4 waves), same 64-patch tile, 80KB LDS -> 2 blocks/CU.
// Inputs fp32 dict order; output fp32. Grid 2048 x 256.

typedef short short8 __attribute__((ext_vector_type(8)));
typedef float f32x4 __attribute__((ext_vector_type(4)));
typedef unsigned uint4v __attribute__((ext_vector_type(4)));

__device__ __forceinline__ unsigned bf16r(float x) {
    unsigned u = __float_as_uint(x);
    return (u + 0x7FFFu + ((u >> 16) & 1u)) >> 16;
}
__device__ __forceinline__ unsigned pack2(float a, float b) {
    return bf16r(a) | (bf16r(b) << 16);
}
__device__ __forceinline__ float ubf(unsigned short h) {
    return __uint_as_float(((unsigned)h) << 16);
}
__device__ __forceinline__ float ulo(unsigned u) { return __uint_as_float(u << 16); }
__device__ __forceinline__ float uhi(unsigned u) { return __uint_as_float(u & 0xFFFF0000u); }

// ---------------- kernel 1: per-(side,b,channel) spatial mean of x_low ----------------
__global__ __launch_bounds__(256) void mean_kernel(const float* __restrict__ x_l,
                                                   const float* __restrict__ x_r,
                                                   float* __restrict__ ws_mean) {
    int bid = blockIdx.x;
    const float* src = (bid >= 1024) ? x_r : x_l;
    const float* p = src + (size_t)(bid & 1023) * 16384;
    int t = threadIdx.x;
    float acc = 0.f;
    #pragma unroll 4
    for (int i = t; i < 16384; i += 256) acc += p[i];
    #pragma unroll
    for (int off = 32; off > 0; off >>= 1) acc += __shfl_down(acc, off, 64);
    __shared__ float red[4];
    if ((t & 63) == 0) red[t >> 6] = acc;
    __syncthreads();
    if (t == 0) ws_mean[bid] = (red[0] + red[1] + red[2] + red[3]) * (1.f / 16384.f);
}

// ---------------- kernel 2: channel gate cm[side][b][128] ----------------
__global__ __launch_bounds__(128) void cm_kernel(const float* __restrict__ ws_mean,
                                                 float* __restrict__ ws_cm,
                                                 const float* __restrict__ Wk,
                                                 const float* __restrict__ bk,
                                                 const float* __restrict__ d_w1,
                                                 const float* __restrict__ d_ln2_g,
                                                 const float* __restrict__ d_ln2_b,
                                                 const float* __restrict__ d_w2) {
    int sb = blockIdx.x;
    __shared__ float km[128];
    int o = threadIdx.x;
    const float* mu = ws_mean + sb * 256;
    float acc = bk[o];
    for (int c = 0; c < 256; ++c) acc = fmaf(Wk[o * 256 + c], mu[c], acc);
    km[o] = acc;
    __syncthreads();
    int h = o >> 4, d = o & 15;
    float t1[8];
    #pragma unroll
    for (int r = 0; r < 8; ++r) {
        float a = 0.f;
        #pragma unroll
        for (int dd = 0; dd < 16; ++dd) a = fmaf(d_w1[r * 16 + dd], km[h * 16 + dd], a);
        t1[r] = a / (1.f + expf(-a));
    }
    float m = 0.f;
    #pragma unroll
    for (int r = 0; r < 8; ++r) m += t1[r];
    m *= 0.125f;
    float v = 0.f;
    #pragma unroll
    for (int r = 0; r < 8; ++r) { float df = t1[r] - m; v = fmaf(df, df, v); }
    float rstd = rsqrtf(v * 0.125f + 1e-5f);
    float cmv = 0.f;
    #pragma unroll
    for (int r = 0; r < 8; ++r)
        cmv = fmaf((t1[r] - m) * rstd * d_ln2_g[r] + d_ln2_b[r], d_w2[d * 8 + r], cmv);
    ws_cm[sb * 128 + o] = cmv;
}

// ---------------- kernel 2b: weights -> bf16 pre-swizzled pool in ws ----------------
// pool (u16): WK=0 [4][32][256]; WV=32768; WQ=65536 [2][64][128]; WQV=81920; WP=98304
__global__ __launch_bounds__(256) void wprep(const float* __restrict__ Wq,
                                             const float* __restrict__ Wqv,
                                             const float* __restrict__ Wk,
                                             const float* __restrict__ Wv,
                                             const float* __restrict__ Wp,
                                             unsigned short* __restrict__ wsp) {
    int bid = blockIdx.x, t = threadIdx.x;
    if (bid < 64) {
        const float* src = (bid < 32) ? Wk : Wv;
        unsigned short* dst = wsp + ((bid < 32) ? 0 : 32768);
        int base = (bid & 31) * 1024;
        #pragma unroll
        for (int i = 0; i < 4; ++i) {
            int el = base + t + 256 * i;
            int q = el >> 13, rem = el & 8191, op = rem >> 8, col = rem & 255;
            dst[q * 8192 + op * 256 + (col ^ ((op & 7) << 3))] =
                (unsigned short)bf16r(src[(q * 32 + op) * 256 + col]);
        }
    } else {
        int g = (bid - 64) >> 4;
        const float* src = (g == 0) ? Wq : (g == 1) ? Wqv : Wp;
        unsigned short* dst = wsp + 65536 + g * 16384;
        int base = ((bid - 64) & 15) * 1024;
        #pragma unroll
        for (int i = 0; i < 4; ++i) {
            int el = base + t + 256 * i;
            int hf = el >> 13, rem = el & 8191, op = rem >> 7, col = rem & 127;
            dst[hf * 8192 + op * 128 + (col ^ ((op & 7) << 3))] =
                (unsigned short)bf16r(src[(hf * 64 + op) * 128 + col]);
        }
    }
}

// LDS offsets (u16) — total 40960 u16 = 80 KB (2 blocks/CU)
#define O_XA 0       // 16384: x_low[64][256] / x_high[128][128] / Q-dump / xc / yn
#define O_WB 16384   // 8192: weight stage
#define O_K  24576   // 8192: K[64][128] u32-swz; after pass1: LG[256][8] @+0, SM f32 @+2048
#define O_V  32768   // 8192: V[64][128] frag-swz
#define LDS_U16 40960

__device__ __forceinline__ short8 frag(const unsigned short* lds, int off, int row, int k, int C2) {
    return *(const short8*)&lds[off + row * C2 + (k ^ ((row & 7) << 3))];
}

// stage fp32 activation tile -> bf16 LDS, frag-swizzled, 16B/lane writes
template<int R, int C2>
__device__ __forceinline__ void stageA16(const float* __restrict__ g, size_t cstride,
                                         unsigned short* lds, int off, int t) {
    #pragma unroll
    for (int it = 0; it < (R * (C2 / 8)) / 256; ++it) {
        int idx = t + it * 256;
        int rr = idx & (R - 1);
        int bc = idx / R;
        float v0 = g[(size_t)(8 * bc + 0) * cstride + rr];
        float v1 = g[(size_t)(8 * bc + 1) * cstride + rr];
        float v2 = g[(size_t)(8 * bc + 2) * cstride + rr];
        float v3 = g[(size_t)(8 * bc + 3) * cstride + rr];
        float v4 = g[(size_t)(8 * bc + 4) * cstride + rr];
        float v5 = g[(size_t)(8 * bc + 5) * cstride + rr];
        float v6 = g[(size_t)(8 * bc + 6) * cstride + rr];
        float v7 = g[(size_t)(8 * bc + 7) * cstride + rr];
        uint4v u = {pack2(v0, v1), pack2(v2, v3), pack2(v4, v5), pack2(v6, v7)};
        *(uint4v*)&lds[off + rr * C2 + ((bc ^ (rr & 7)) << 3)] = u;
    }
}

// linear 16KB (8192 u16) copy of pre-swizzled bf16 weights into WB
__device__ __forceinline__ void stageW16(const unsigned short* __restrict__ src,
                                         unsigned short* lds, int t) {
    #pragma unroll
    for (int c = 0; c < 4; ++c) {
        int u = (c * 256 + t) * 8;
        *(short8*)&lds[O_WB + u] = *(const short8*)&src[u];
    }
}

#define ZERO4(A) do { _Pragma("unroll") for (int z_ = 0; z_ < 4; ++z_) A[z_] = (f32x4){0.f,0.f,0.f,0.f}; } while (0)

// two m-tiles (w and w+4) x 4 n-tiles over 128-col A/B
#define GEMM8(A0, A1) do {                                                         \
    _Pragma("unroll")                                                              \
    for (int kc_ = 0; kc_ < 4; ++kc_) {                                            \
      short8 af0_ = frag(lds, O_XA, 16 * w + lm, kc_ * 32 + lg * 8, 128);          \
      short8 af1_ = frag(lds, O_XA, 16 * (w + 4) + lm, kc_ * 32 + lg * 8, 128);    \
      _Pragma("unroll")                                                            \
      for (int n_ = 0; n_ < 4; ++n_) {                                             \
        short8 bf_ = frag(lds, O_WB, 16 * n_ + lm, kc_ * 32 + lg * 8, 128);        \
        A0[n_] = __builtin_amdgcn_mfma_f32_16x16x32_bf16(af0_, bf_, A0[n_], 0, 0, 0); \
        A1[n_] = __builtin_amdgcn_mfma_f32_16x16x32_bf16(af1_, bf_, A1[n_], 0, 0, 0); \
      } }                                                                          \
  } while (0)

#define QDUMP(ACC, OBASE, MT) do {                                                 \
    _Pragma("unroll")                                                              \
    for (int n_ = 0; n_ < 4; ++n_) {                                               \
      int o_ = (OBASE) + 16 * n_ + lm;                                             \
      float bb_ = bq[o_];                                                          \
      _Pragma("unroll")                                                            \
      for (int r_ = 0; r_ < 4; ++r_) {                                             \
        int row_ = 16 * (w + (MT)) + 4 * lg + r_;                                  \
        lds[O_XA + row_ * 128 + ((((o_ >> 1) ^ (row_ & 31)) << 1) | (o_ & 1))] =   \
            (unsigned short)bf16r(ACC[n_][r_] + bb_);                              \
      } } } while (0)

#define COMBINE(ACC, DY, NH, MT) do {                                              \
    _Pragma("unroll")                                                              \
    for (int n_ = 0; n_ < 4; ++n_) {                                               \
      int nt_ = 4 * (NH) + n_;                                                     \
      int o_ = 16 * nt_ + lm;                                                      \
      float bias_ = bqv[o_];                                                       \
      float cmv_ = cmp[o_];                                                        \
      _Pragma("unroll")                                                            \
      for (int r_ = 0; r_ < 4; ++r_) {                                             \
        int row_ = 16 * (w + (MT)) + 4 * lg + r_;                                  \
        int jj_ = row_ >> 1;                                                       \
        float vq_ = ACC[n_][r_] + bias_;                                           \
        float aw_ = ubf(lgp[((DY) * 128 + row_) * 8 + (nt_ ^ (row_ & 7))]);        \
        float vv_ = ubf(lds[O_V + jj_ * 128 + (o_ ^ ((jj_ & 7) << 3))]);           \
        float wg_ = 1.f / (1.f + __expf(-(smk[jj_ * 8 + nt_] + cmv_)));            \
        float xc_ = (1.f - wg_) * aw_ * vv_ * 4.f + wg_ * vq_;                     \
        lds[O_XA + row_ * 128 + (o_ ^ ((row_ & 7) << 3))] = (unsigned short)bf16r(xc_); \
      } } } while (0)

#define LN_YN(PA, PB, MT) do {                                                     \
    _Pragma("unroll")                                                              \
    for (int r_ = 0; r_ < 4; ++r_) {                                               \
      float ps_ = 0.f, pq_ = 0.f;                                                  \
      _Pragma("unroll")                                                            \
      for (int n_ = 0; n_ < 4; ++n_) {                                             \
        float y0_ = PA[n_][r_] + bp[16 * n_ + lm];                                 \
        float y1_ = PB[n_][r_] + bp[64 + 16 * n_ + lm];                            \
        ps_ += y0_ + y1_;                                                          \
        pq_ = fmaf(y0_, y0_, fmaf(y1_, y1_, pq_));                                 \
      }                                                                            \
      _Pragma("unroll")                                                            \
      for (int d_ = 1; d_ < 16; d_ <<= 1) {                                        \
        ps_ += __shfl_xor(ps_, d_, 64); pq_ += __shfl_xor(pq_, d_, 64);            \
      }                                                                            \
      float mn_ = ps_ * (1.f / 128.f);                                             \
      float rs_ = rsqrtf(pq_ * (1.f / 128.f) - mn_ * mn_ + 1e-5f);                 \
      int row_ = 16 * (w + (MT)) + 4 * lg + r_;                                    \
      _Pragma("unroll")                                                            \
      for (int n_ = 0; n_ < 4; ++n_) {                                             \
        int oA_ = 16 * n_ + lm, oB_ = 64 + 16 * n_ + lm;                           \
        float ynA_ = (PA[n_][r_] + bp[oA_] - mn_) * rs_ * ln_g[oA_] + ln_b[oA_];   \
        float ynB_ = (PB[n_][r_] + bp[oB_] - mn_) * rs_ * ln_g[oB_] + ln_b[oB_];   \
        lds[O_XA + row_ * 128 + ((((oA_ >> 1) ^ (row_ & 31)) << 1) | (oA_ & 1))] = (unsigned short)bf16r(ynA_); \
        lds[O_XA + row_ * 128 + ((((oB_ >> 1) ^ (row_ & 31)) << 1) | (oB_ & 1))] = (unsigned short)bf16r(ynB_); \
      }                                                                            \
    } } while (0)

// pass-1 per-dy body (DY literal, LGR = per-dy logit register array)
#define PASS1_DY(DY, LGR) do {                                                     \
    __syncthreads();                                                               \
    stageA16<128, 128>(hb0 + (DY) * 256, 65536, lds, O_XA, t);                     \
    stageW16(wsp + 65536, lds, t);                                                 \
    __syncthreads();                                                               \
    f32x4 qA0[4], qA1[4], qB0[4], qB1[4];                                          \
    ZERO4(qA0); ZERO4(qA1);                                                        \
    GEMM8(qA0, qA1);                                                               \
    __syncthreads();                                                               \
    stageW16(wsp + 65536 + 8192, lds, t);                                          \
    __syncthreads();                                                               \
    ZERO4(qB0); ZERO4(qB1);                                                        \
    GEMM8(qB0, qB1);                                                               \
    __syncthreads();                                                               \
    QDUMP(qA0, 0, 0); QDUMP(qA1, 0, 4); QDUMP(qB0, 64, 0); QDUMP(qB1, 64, 4);      \
    __syncthreads();                                                               \
    _Pragma("unroll")                                                              \
    for (int ii = 0; ii < 4; ++ii) {                                               \
      int h_ = 2 * ii + hsel;                                                      \
      int tok_ = irow >> 1;                                                        \
      float sq = 0.f, sqq = 0.f, sgw = 0.f, sqk = 0.f;                             \
      _Pragma("unroll")                                                            \
      for (int d2 = 0; d2 < 8; ++d2) {                                             \
        unsigned qu = *(const unsigned*)&lds[O_XA + irow * 128 + (((h_ * 8 + d2) ^ (irow & 31)) << 1)]; \
        unsigned ku = *(const unsigned*)&lds[O_K + tok_ * 128 + (((h_ * 8 + d2) ^ (tok_ & 31)) << 1)];  \
        float q0 = ulo(qu), q1 = uhi(qu);                                          \
        float k0 = ulo(ku), k1 = uhi(ku);                                          \
        sq += q0 + q1;                                                             \
        sqq = fmaf(q0, q0, fmaf(q1, q1, sqq));                                     \
        sgw = fmaf(q0, gwv[2 * d2], fmaf(q1, gwv[2 * d2 + 1], sgw));               \
        sqk = fmaf(q0, k0, fmaf(q1, k1, sqk));                                     \
      }                                                                            \
      LGR[ii] = sqk * 0.25f;                                                       \
      float mn_ = sq * 0.0625f;                                                    \
      float rs_ = rsqrtf(sqq * 0.0625f - mn_ * mn_ + 1e-5f);                       \
      sdacc[ii] += rs_ * (sgw - mn_ * S1) + S2;                                    \
    }                                                                              \
  } while (0)

// ---------------- kernel 3: fused main ----------------
__global__ __launch_bounds__(256, 2) void pafm_v9(
    const float* __restrict__ x_l,  const float* __restrict__ x_r,
    const float* __restrict__ x_lh, const float* __restrict__ x_rh,
    const float* __restrict__ bq,   const float* __restrict__ bqv,
    const float* __restrict__ bk,   const float* __restrict__ bv,
    const float* __restrict__ bp,
    const float* __restrict__ ln_g, const float* __restrict__ ln_b,
    const float* __restrict__ d_ln1_g, const float* __restrict__ d_ln1_b,
    const float* __restrict__ d_wsv,
    const float* __restrict__ ws_cm,
    const unsigned short* __restrict__ wsp,
    float* __restrict__ out) {

    __shared__ unsigned short lds[LDS_U16];
    unsigned short* lgp = &lds[O_K];            // logits/aw [256][8] (after pass 1)
    float* smk = (float*)&lds[O_K + 2048];      // sm f32[512]

    int bid = blockIdx.x;                 // s(1)|b(2)|i0(7)|jb(1)
    int s  = bid >> 10;
    int b  = (bid >> 8) & 3;
    int i0 = (bid >> 1) & 127;
    int j0 = (bid & 1) * 64;

    int t = threadIdx.x, w = t >> 6, l = t & 63, lm = l & 15, lg = l >> 4;
    int irow = t & 127, hsel = t >> 7;

    const float* xlow  = s ? x_r  : x_l;
    const float* xhigh = s ? x_rh : x_lh;
    const float* cmp   = ws_cm + (s * 4 + b) * 128;

    // DANE coefficients
    float gwv[16], S1 = 0.f, S2 = 0.f;
    #pragma unroll
    for (int d = 0; d < 16; ++d) {
        float wsd = d_wsv[d];
        gwv[d] = d_ln1_g[d] * wsd;
        S1 += gwv[d];
        S2 += d_ln1_b[d] * wsd;
    }

    const float* lowb = xlow + ((size_t)(b * 256) * 128 + i0) * 128 + j0;
    const float* hb0  = xhigh + ((size_t)(b * 128) * 256 + 2 * i0) * 256 + 2 * j0;

    // ---- KV phase: x_low staged once; 8 weight quarters (4 Wk + 4 Wv) ----
    stageA16<64, 256>(lowb, 16384, lds, O_XA, t);
    #pragma unroll 1
    for (int qq = 0; qq < 8; ++qq) {
        __syncthreads();
        stageW16(wsp + qq * 8192, lds, t);
        __syncthreads();
        f32x4 a0 = (f32x4){0.f, 0.f, 0.f, 0.f};
        f32x4 a1 = (f32x4){0.f, 0.f, 0.f, 0.f};
        #pragma unroll
        for (int kc = 0; kc < 8; ++kc) {
            short8 af = frag(lds, O_XA, 16 * w + lm, kc * 32 + lg * 8, 256);
            short8 b0 = frag(lds, O_WB, lm, kc * 32 + lg * 8, 256);
            a0 = __builtin_amdgcn_mfma_f32_16x16x32_bf16(af, b0, a0, 0, 0, 0);
            short8 b1 = frag(lds, O_WB, 16 + lm, kc * 32 + lg * 8, 256);
            a1 = __builtin_amdgcn_mfma_f32_16x16x32_bf16(af, b1, a1, 0, 0, 0);
        }
        int o0 = (qq & 3) * 32 + lm, o1 = o0 + 16;
        if (qq < 4) {
            float bb0 = bk[o0], bb1 = bk[o1];
            #pragma unroll
            for (int r = 0; r < 4; ++r) {
                int tok = 16 * w + 4 * lg + r;
                lds[O_K + tok * 128 + ((((o0 >> 1) ^ (tok & 31)) << 1) | (o0 & 1))] =
                    (unsigned short)bf16r(a0[r] + bb0);
                lds[O_K + tok * 128 + ((((o1 >> 1) ^ (tok & 31)) << 1) | (o1 & 1))] =
                    (unsigned short)bf16r(a1[r] + bb1);
            }
        } else {
            float bb0 = bv[o0], bb1 = bv[o1];
            #pragma unroll
            for (int r = 0; r < 4; ++r) {
                int tok = 16 * w + 4 * lg + r;
                lds[O_V + tok * 128 + (o0 ^ ((tok & 7) << 3))] = (unsigned short)bf16r(a0[r] + bb0);
                lds[O_V + tok * 128 + (o1 ^ ((tok & 7) << 3))] = (unsigned short)bf16r(a1[r] + bb1);
            }
        }
    }

    // ---- pass 1: Q GEMM + item-loop logits/DANE ----
    float lgr0[4], lgr1[4];
    float sdacc[4] = {0.f, 0.f, 0.f, 0.f};
    PASS1_DY(0, lgr0);
    PASS1_DY(1, lgr1);
    __syncthreads();              // all K reads done -> K region reusable

    // write logits (bf16) + sm (f32) into K region
    #pragma unroll
    for (int ii = 0; ii < 4; ++ii) {
        int h = 2 * ii + hsel;
        lgp[irow * 8 + (h ^ (irow & 7))]         = (unsigned short)bf16r(lgr0[ii]);
        lgp[(128 + irow) * 8 + (h ^ (irow & 7))] = (unsigned short)bf16r(lgr1[ii]);
        float sdt = sdacc[ii] + __shfl_xor(sdacc[ii], 1, 64);
        if ((t & 1) == 0) smk[(irow >> 1) * 8 + h] = sdt * 0.25f;
    }
    __syncthreads();

    // ---- softmax over 4 px per (jj, h): 512 items over 256 threads ----
    #pragma unroll
    for (int k2 = 0; k2 < 2; ++k2) {
        int item = t + 256 * k2;
        int jj = item >> 3, h = item & 7;
        int ra = 2 * jj, rb2 = 2 * jj + 1;
        int a0 = ra * 8 + (h ^ (ra & 7));
        int a1 = rb2 * 8 + (h ^ (rb2 & 7));
        int a2 = (128 + ra) * 8 + (h ^ (ra & 7));
        int a3 = (128 + rb2) * 8 + (h ^ (rb2 & 7));
        float l0 = ubf(lgp[a0]), l1 = ubf(lgp[a1]), l2 = ubf(lgp[a2]), l3 = ubf(lgp[a3]);
        float mx = fmaxf(fmaxf(l0, l1), fmaxf(l2, l3));
        float e0 = __expf(l0 - mx), e1 = __expf(l1 - mx);
        float e2 = __expf(l2 - mx), e3 = __expf(l3 - mx);
        float inv = 1.f / (e0 + e1 + e2 + e3);
        lgp[a0] = (unsigned short)bf16r(e0 * inv);
        lgp[a1] = (unsigned short)bf16r(e1 * inv);
        lgp[a2] = (unsigned short)bf16r(e2 * inv);
        lgp[a3] = (unsigned short)bf16r(e3 * inv);
    }

    // ---- pass 2 per dy: VQ -> combine -> P -> LN -> store ----
    #pragma unroll 1
    for (int dy = 0; dy < 2; ++dy) {
        __syncthreads();
        stageA16<128, 128>(hb0 + dy * 256, 65536, lds, O_XA, t);
        stageW16(wsp + 81920, lds, t);          // WQV half 0
        __syncthreads();
        f32x4 vA0[4], vA1[4], vB0[4], vB1[4];
        ZERO4(vA0); ZERO4(vA1);
        GEMM8(vA0, vA1);
        __syncthreads();
        stageW16(wsp + 81920 + 8192, lds, t);   // WQV half 1
        __syncthreads();
        ZERO4(vB0); ZERO4(vB1);
        GEMM8(vB0, vB1);
        __syncthreads();                        // VQ reads of XA done
        COMBINE(vA0, dy, 0, 0); COMBINE(vA1, dy, 0, 4);
        COMBINE(vB0, dy, 1, 0); COMBINE(vB1, dy, 1, 4);
        stageW16(wsp + 98304, lds, t);          // WP half 0
        __syncthreads();                        // xc + WP visible

        f32x4 pA0[4], pA1[4], pB0[4], pB1[4];
        ZERO4(pA0); ZERO4(pA1);
        GEMM8(pA0, pA1);
        __syncthreads();
        stageW16(wsp + 98304 + 8192, lds, t);   // WP half 1
        __syncthreads();
        ZERO4(pB0); ZERO4(pB1);
        GEMM8(pB0, pB1);
        __syncthreads();                        // P reads of XA done

        LN_YN(pA0, pB0, 0);
        LN_YN(pA1, pB1, 4);
        __syncthreads();
        // coalesced store + residual (global, L2-hot)
        {
            const float* rb = hb0 + dy * 256;
            float* ob = out + (size_t)s * 33554432
                      + ((size_t)(b * 128)) * 65536 + (size_t)(2 * i0 + dy) * 256 + 2 * j0;
            int ph = t & 127, cq = t >> 7;
            #pragma unroll
            for (int it2 = 0; it2 < 32; ++it2) {
                int c4 = it2 * 2 + cq;
                unsigned uv = *(const unsigned*)&lds[O_XA + ph * 128 + ((c4 ^ (ph & 31)) << 1)];
                size_t off0 = (size_t)(2 * c4) * 65536 + ph;
                size_t off1 = off0 + 65536;
                ob[off0] = rb[off0] + ulo(uv);
                ob[off1] = rb[off1] + uhi(uv);
            }
        }
    }
}

extern "C" void kernel_launch(void* const* d_in, const int* in_sizes, int n_in,
                              void* d_out, int out_size, void* d_ws, size_t ws_size,
                              hipStream_t stream) {
    const float* x_l   = (const float*)d_in[0];
    const float* x_r   = (const float*)d_in[1];
    const float* x_lh  = (const float*)d_in[2];
    const float* x_rh  = (const float*)d_in[3];
    const float* Wq    = (const float*)d_in[4];
    const float* bq    = (const float*)d_in[5];
    const float* Wqv   = (const float*)d_in[6];
    const float* bqv   = (const float*)d_in[7];
    const float* Wk    = (const float*)d_in[8];
    const float* bk    = (const float*)d_in[9];
    const float* Wv    = (const float*)d_in[10];
    const float* bv    = (const float*)d_in[11];
    const float* Wp    = (const float*)d_in[12];
    const float* bp    = (const float*)d_in[13];
    const float* ln_g  = (const float*)d_in[14];
    const float* ln_b  = (const float*)d_in[15];
    const float* dln1g = (const float*)d_in[16];
    const float* dln1b = (const float*)d_in[17];
    const float* d_wsv = (const float*)d_in[18];
    const float* d_w1  = (const float*)d_in[19];
    const float* dln2g = (const float*)d_in[20];
    const float* dln2b = (const float*)d_in[21];
    const float* d_w2  = (const float*)d_in[22];

    float* out = (float*)d_out;
    float* ws_mean = (float*)d_ws;                                 // 2048 f
    float* ws_cm   = ws_mean + 2048;                               // 1024 f
    unsigned short* wsp = (unsigned short*)((char*)d_ws + 16384);  // 224 KB bf16 pool

    mean_kernel<<<2048, 256, 0, stream>>>(x_l, x_r, ws_mean);
    wprep<<<112, 256, 0, stream>>>(Wq, Wqv, Wk, Wv, Wp, wsp);
    cm_kernel<<<8, 128, 0, stream>>>(ws_mean, ws_cm, Wk, bk, d_w1, dln2g, dln2b, d_w2);
    pafm_v9<<<2048, 256, 0, stream>>>(x_l, x_r, x_lh, x_rh,
                                      bq, bqv, bk, bv, bp, ln_g, ln_b,
                                      dln1g, dln1b, d_wsv, ws_cm, wsp, out);
}

// Round 16
// 1117.323 us; speedup vs baseline: 1.3644x; 1.3644x over previous
//
#include <hip/hip_runtime.h>
#include <hip/hip_bf16.h>
#include <math.h>

// PAFM fused v10: 32-patch blocks, 256 thr (4 waves), 51KB LDS -> 3 blocks/CU,
// per-wave work identical to v8 (spill-free 32-float acc sets).
// Inputs fp32 dict order; output fp32. Grid 4096 x 256.

typedef short short8 __attribute__((ext_vector_type(8)));
typedef float f32x4 __attribute__((ext_vector_type(4)));
typedef unsigned uint4v __attribute__((ext_vector_type(4)));

__device__ __forceinline__ unsigned bf16r(float x) {
    unsigned u = __float_as_uint(x);
    return (u + 0x7FFFu + ((u >> 16) & 1u)) >> 16;
}
__device__ __forceinline__ unsigned pack2(float a, float b) {
    return bf16r(a) | (bf16r(b) << 16);
}
__device__ __forceinline__ float ubf(unsigned short h) {
    return __uint_as_float(((unsigned)h) << 16);
}
__device__ __forceinline__ float ulo(unsigned u) { return __uint_as_float(u << 16); }
__device__ __forceinline__ float uhi(unsigned u) { return __uint_as_float(u & 0xFFFF0000u); }

// ---------------- kernel 1: per-(side,b,channel) spatial mean of x_low ----------------
__global__ __launch_bounds__(256) void mean_kernel(const float* __restrict__ x_l,
                                                   const float* __restrict__ x_r,
                                                   float* __restrict__ ws_mean) {
    int bid = blockIdx.x;
    const float* src = (bid >= 1024) ? x_r : x_l;
    const float* p = src + (size_t)(bid & 1023) * 16384;
    int t = threadIdx.x;
    float acc = 0.f;
    #pragma unroll 4
    for (int i = t; i < 16384; i += 256) acc += p[i];
    #pragma unroll
    for (int off = 32; off > 0; off >>= 1) acc += __shfl_down(acc, off, 64);
    __shared__ float red[4];
    if ((t & 63) == 0) red[t >> 6] = acc;
    __syncthreads();
    if (t == 0) ws_mean[bid] = (red[0] + red[1] + red[2] + red[3]) * (1.f / 16384.f);
}

// ---------------- kernel 2: channel gate cm[side][b][128] ----------------
__global__ __launch_bounds__(128) void cm_kernel(const float* __restrict__ ws_mean,
                                                 float* __restrict__ ws_cm,
                                                 const float* __restrict__ Wk,
                                                 const float* __restrict__ bk,
                                                 const float* __restrict__ d_w1,
                                                 const float* __restrict__ d_ln2_g,
                                                 const float* __restrict__ d_ln2_b,
                                                 const float* __restrict__ d_w2) {
    int sb = blockIdx.x;
    __shared__ float km[128];
    int o = threadIdx.x;
    const float* mu = ws_mean + sb * 256;
    float acc = bk[o];
    for (int c = 0; c < 256; ++c) acc = fmaf(Wk[o * 256 + c], mu[c], acc);
    km[o] = acc;
    __syncthreads();
    int h = o >> 4, d = o & 15;
    float t1[8];
    #pragma unroll
    for (int r = 0; r < 8; ++r) {
        float a = 0.f;
        #pragma unroll
        for (int dd = 0; dd < 16; ++dd) a = fmaf(d_w1[r * 16 + dd], km[h * 16 + dd], a);
        t1[r] = a / (1.f + expf(-a));
    }
    float m = 0.f;
    #pragma unroll
    for (int r = 0; r < 8; ++r) m += t1[r];
    m *= 0.125f;
    float v = 0.f;
    #pragma unroll
    for (int r = 0; r < 8; ++r) { float df = t1[r] - m; v = fmaf(df, df, v); }
    float rstd = rsqrtf(v * 0.125f + 1e-5f);
    float cmv = 0.f;
    #pragma unroll
    for (int r = 0; r < 8; ++r)
        cmv = fmaf((t1[r] - m) * rstd * d_ln2_g[r] + d_ln2_b[r], d_w2[d * 8 + r], cmv);
    ws_cm[sb * 128 + o] = cmv;
}

// ---------------- kernel 2b: weights -> bf16 pre-swizzled pool in ws ----------------
// pool (u16): WK=0 [4][32][256]; WV=32768; WQ=65536 [2][64][128]; WQV=81920; WP=98304
__global__ __launch_bounds__(256) void wprep(const float* __restrict__ Wq,
                                             const float* __restrict__ Wqv,
                                             const float* __restrict__ Wk,
                                             const float* __restrict__ Wv,
                                             const float* __restrict__ Wp,
                                             unsigned short* __restrict__ wsp) {
    int bid = blockIdx.x, t = threadIdx.x;
    if (bid < 64) {
        const float* src = (bid < 32) ? Wk : Wv;
        unsigned short* dst = wsp + ((bid < 32) ? 0 : 32768);
        int base = (bid & 31) * 1024;
        #pragma unroll
        for (int i = 0; i < 4; ++i) {
            int el = base + t + 256 * i;
            int q = el >> 13, rem = el & 8191, op = rem >> 8, col = rem & 255;
            dst[q * 8192 + op * 256 + (col ^ ((op & 7) << 3))] =
                (unsigned short)bf16r(src[(q * 32 + op) * 256 + col]);
        }
    } else {
        int g = (bid - 64) >> 4;
        const float* src = (g == 0) ? Wq : (g == 1) ? Wqv : Wp;
        unsigned short* dst = wsp + 65536 + g * 16384;
        int base = ((bid - 64) & 15) * 1024;
        #pragma unroll
        for (int i = 0; i < 4; ++i) {
            int el = base + t + 256 * i;
            int hf = el >> 13, rem = el & 8191, op = rem >> 7, col = rem & 127;
            dst[hf * 8192 + op * 128 + (col ^ ((op & 7) << 3))] =
                (unsigned short)bf16r(src[(hf * 64 + op) * 128 + col]);
        }
    }
}

// LDS offsets (u16) — total 26112 u16 = 51 KB (3 blocks/CU)
#define O_XA 0       // 8192: x_low[32][256] / x_high[64][128] / Q-dump / xc / yn
#define O_WB 8192    // 8192: weight stage
#define O_K  16384   // 4096: K[32][128] u32-pair swizzle
#define O_V  20480   // 4096: V[32][128] frag swizzle
#define O_LG 24576   // 1024: logits/aw [2 dy][64 rows][8 heads]
#define O_SM 25600   // 512 u16 = 256 f32: sm[32][8]
#define LDS_U16 26112

__device__ __forceinline__ short8 frag(const unsigned short* lds, int off, int row, int k, int C2) {
    return *(const short8*)&lds[off + row * C2 + (k ^ ((row & 7) << 3))];
}

// stage fp32 activation tile -> bf16 LDS, frag-swizzled, 16B/lane writes
template<int R, int C2>
__device__ __forceinline__ void stageA16(const float* __restrict__ g, size_t cstride,
                                         unsigned short* lds, int off, int t) {
    #pragma unroll
    for (int it = 0; it < (R * (C2 / 8)) / 256; ++it) {
        int idx = t + it * 256;
        int rr = idx & (R - 1);
        int bc = idx / R;
        float v0 = g[(size_t)(8 * bc + 0) * cstride + rr];
        float v1 = g[(size_t)(8 * bc + 1) * cstride + rr];
        float v2 = g[(size_t)(8 * bc + 2) * cstride + rr];
        float v3 = g[(size_t)(8 * bc + 3) * cstride + rr];
        float v4 = g[(size_t)(8 * bc + 4) * cstride + rr];
        float v5 = g[(size_t)(8 * bc + 5) * cstride + rr];
        float v6 = g[(size_t)(8 * bc + 6) * cstride + rr];
        float v7 = g[(size_t)(8 * bc + 7) * cstride + rr];
        uint4v u = {pack2(v0, v1), pack2(v2, v3), pack2(v4, v5), pack2(v6, v7)};
        *(uint4v*)&lds[off + rr * C2 + ((bc ^ (rr & 7)) << 3)] = u;
    }
}

// linear 16KB (8192 u16) copy of pre-swizzled bf16 weights into WB
__device__ __forceinline__ void stageW16(const unsigned short* __restrict__ src,
                                         unsigned short* lds, int t) {
    #pragma unroll
    for (int c = 0; c < 4; ++c) {
        int u = (c * 256 + t) * 8;
        *(short8*)&lds[O_WB + u] = *(const short8*)&src[u];
    }
}

#define ZERO4(A) do { _Pragma("unroll") for (int z_ = 0; z_ < 4; ++z_) A[z_] = (f32x4){0.f,0.f,0.f,0.f}; } while (0)

// one m-tile (w) x 4 n-tiles over 128-col A (XA, 64 rows) / B (WB, 64 rows)
#define GEMM4(ACC) do {                                                            \
    _Pragma("unroll")                                                              \
    for (int kc_ = 0; kc_ < 4; ++kc_) {                                            \
      short8 af_ = frag(lds, O_XA, 16 * w + lm, kc_ * 32 + lg * 8, 128);           \
      _Pragma("unroll")                                                            \
      for (int n_ = 0; n_ < 4; ++n_) {                                             \
        short8 bf_ = frag(lds, O_WB, 16 * n_ + lm, kc_ * 32 + lg * 8, 128);        \
        ACC[n_] = __builtin_amdgcn_mfma_f32_16x16x32_bf16(af_, bf_, ACC[n_], 0, 0, 0); \
      } }                                                                          \
  } while (0)

#define QDUMP(ACC, OBASE) do {                                                     \
    _Pragma("unroll")                                                              \
    for (int n_ = 0; n_ < 4; ++n_) {                                               \
      int o_ = (OBASE) + 16 * n_ + lm;                                             \
      float bb_ = bq[o_];                                                          \
      _Pragma("unroll")                                                            \
      for (int r_ = 0; r_ < 4; ++r_) {                                             \
        int row_ = 16 * w + 4 * lg + r_;                                           \
        lds[O_XA + row_ * 128 + ((((o_ >> 1) ^ (row_ & 31)) << 1) | (o_ & 1))] =   \
            (unsigned short)bf16r(ACC[n_][r_] + bb_);                              \
      } } } while (0)

#define COMBINE(ACC, DY, NH) do {                                                  \
    _Pragma("unroll")                                                              \
    for (int n_ = 0; n_ < 4; ++n_) {                                               \
      int nt_ = 4 * (NH) + n_;                                                     \
      int o_ = 16 * nt_ + lm;                                                      \
      float bias_ = bqv[o_];                                                       \
      float cmv_ = cmp[o_];                                                        \
      _Pragma("unroll")                                                            \
      for (int r_ = 0; r_ < 4; ++r_) {                                             \
        int row_ = 16 * w + 4 * lg + r_;                                           \
        int jj_ = row_ >> 1;                                                       \
        float vq_ = ACC[n_][r_] + bias_;                                           \
        float aw_ = ubf(lds[O_LG + (DY) * 512 + row_ * 8 + (nt_ ^ (row_ & 7))]);   \
        float vv_ = ubf(lds[O_V + jj_ * 128 + (o_ ^ ((jj_ & 7) << 3))]);           \
        float wg_ = 1.f / (1.f + __expf(-(smk[jj_ * 8 + nt_] + cmv_)));            \
        float xc_ = (1.f - wg_) * aw_ * vv_ * 4.f + wg_ * vq_;                     \
        lds[O_XA + row_ * 128 + (o_ ^ ((row_ & 7) << 3))] = (unsigned short)bf16r(xc_); \
      } } } while (0)

#define LN_YN(PA, PB) do {                                                         \
    _Pragma("unroll")                                                              \
    for (int r_ = 0; r_ < 4; ++r_) {                                               \
      float ps_ = 0.f, pq_ = 0.f;                                                  \
      _Pragma("unroll")                                                            \
      for (int n_ = 0; n_ < 4; ++n_) {                                             \
        float y0_ = PA[n_][r_] + bp[16 * n_ + lm];                                 \
        float y1_ = PB[n_][r_] + bp[64 + 16 * n_ + lm];                            \
        ps_ += y0_ + y1_;                                                          \
        pq_ = fmaf(y0_, y0_, fmaf(y1_, y1_, pq_));                                 \
      }                                                                            \
      _Pragma("unroll")                                                            \
      for (int d_ = 1; d_ < 16; d_ <<= 1) {                                        \
        ps_ += __shfl_xor(ps_, d_, 64); pq_ += __shfl_xor(pq_, d_, 64);            \
      }                                                                            \
      float mn_ = ps_ * (1.f / 128.f);                                             \
      float rs_ = rsqrtf(pq_ * (1.f / 128.f) - mn_ * mn_ + 1e-5f);                 \
      int row_ = 16 * w + 4 * lg + r_;                                             \
      _Pragma("unroll")                                                            \
      for (int n_ = 0; n_ < 4; ++n_) {                                             \
        int oA_ = 16 * n_ + lm, oB_ = 64 + 16 * n_ + lm;                           \
        float ynA_ = (PA[n_][r_] + bp[oA_] - mn_) * rs_ * ln_g[oA_] + ln_b[oA_];   \
        float ynB_ = (PB[n_][r_] + bp[oB_] - mn_) * rs_ * ln_g[oB_] + ln_b[oB_];   \
        lds[O_XA + row_ * 128 + ((((oA_ >> 1) ^ (row_ & 31)) << 1) | (oA_ & 1))] = (unsigned short)bf16r(ynA_); \
        lds[O_XA + row_ * 128 + ((((oB_ >> 1) ^ (row_ & 31)) << 1) | (oB_ & 1))] = (unsigned short)bf16r(ynB_); \
      }                                                                            \
    } } while (0)

// pass-1 per-dy body (DY literal, LGR = per-dy 2-logit register array)
#define PASS1_DY(DY, LGR) do {                                                     \
    __syncthreads();                                                               \
    stageA16<64, 128>(hb0 + (DY) * 256, 65536, lds, O_XA, t);                      \
    stageW16(wsp + 65536, lds, t);                                                 \
    __syncthreads();                                                               \
    f32x4 qA[4], qB[4];                                                            \
    ZERO4(qA); GEMM4(qA);                                                          \
    __syncthreads();                                                               \
    stageW16(wsp + 65536 + 8192, lds, t);                                          \
    __syncthreads();                                                               \
    ZERO4(qB); GEMM4(qB);                                                          \
    __syncthreads();                                                               \
    QDUMP(qA, 0); QDUMP(qB, 64);                                                   \
    __syncthreads();                                                               \
    _Pragma("unroll")                                                              \
    for (int ii = 0; ii < 2; ++ii) {                                               \
      int h_ = hgrp + 4 * ii;                                                      \
      int tok_ = irow >> 1;                                                        \
      float sq = 0.f, sqq = 0.f, sgw = 0.f, sqk = 0.f;                             \
      _Pragma("unroll")                                                            \
      for (int d2 = 0; d2 < 8; ++d2) {                                             \
        unsigned qu = *(const unsigned*)&lds[O_XA + irow * 128 + (((h_ * 8 + d2) ^ (irow & 31)) << 1)]; \
        unsigned ku = *(const unsigned*)&lds[O_K + tok_ * 128 + (((h_ * 8 + d2) ^ tok_) << 1)];         \
        float q0 = ulo(qu), q1 = uhi(qu);                                          \
        float k0 = ulo(ku), k1 = uhi(ku);                                          \
        sq += q0 + q1;                                                             \
        sqq = fmaf(q0, q0, fmaf(q1, q1, sqq));                                     \
        sgw = fmaf(q0, gwv[2 * d2], fmaf(q1, gwv[2 * d2 + 1], sgw));               \
        sqk = fmaf(q0, k0, fmaf(q1, k1, sqk));                                     \
      }                                                                            \
      LGR[ii] = sqk * 0.25f;                                                       \
      float mn_ = sq * 0.0625f;                                                    \
      float rs_ = rsqrtf(sqq * 0.0625f - mn_ * mn_ + 1e-5f);                       \
      sdacc[ii] += rs_ * (sgw - mn_ * S1) + S2;                                    \
    }                                                                              \
  } while (0)

// ---------------- kernel 3: fused main ----------------
__global__ __launch_bounds__(256, 3) void pafm_v10(
    const float* __restrict__ x_l,  const float* __restrict__ x_r,
    const float* __restrict__ x_lh, const float* __restrict__ x_rh,
    const float* __restrict__ bq,   const float* __restrict__ bqv,
    const float* __restrict__ bk,   const float* __restrict__ bv,
    const float* __restrict__ bp,
    const float* __restrict__ ln_g, const float* __restrict__ ln_b,
    const float* __restrict__ d_ln1_g, const float* __restrict__ d_ln1_b,
    const float* __restrict__ d_wsv,
    const float* __restrict__ ws_cm,
    const unsigned short* __restrict__ wsp,
    float* __restrict__ out) {

    __shared__ unsigned short lds[LDS_U16];
    float* smk = (float*)&lds[O_SM];      // sm f32[256]

    int bid = blockIdx.x;                 // s(1)|b(2)|i0(7)|jb(2)
    int s  = bid >> 11;
    int b  = (bid >> 9) & 3;
    int i0 = (bid >> 2) & 127;
    int j0 = (bid & 3) * 32;

    int t = threadIdx.x, w = t >> 6, l = t & 63, lm = l & 15, lg = l >> 4;
    int irow = t & 63, hgrp = t >> 6;

    const float* xlow  = s ? x_r  : x_l;
    const float* xhigh = s ? x_rh : x_lh;
    const float* cmp   = ws_cm + (s * 4 + b) * 128;

    // DANE coefficients
    float gwv[16], S1 = 0.f, S2 = 0.f;
    #pragma unroll
    for (int d = 0; d < 16; ++d) {
        float wsd = d_wsv[d];
        gwv[d] = d_ln1_g[d] * wsd;
        S1 += gwv[d];
        S2 += d_ln1_b[d] * wsd;
    }

    const float* lowb = xlow + ((size_t)(b * 256) * 128 + i0) * 128 + j0;
    const float* hb0  = xhigh + ((size_t)(b * 128) * 256 + 2 * i0) * 256 + 2 * j0;

    // ---- KV phase: x_low[32][256] staged once; 8 weight quarters (4 Wk + 4 Wv) ----
    stageA16<32, 256>(lowb, 16384, lds, O_XA, t);
    int mt = w & 1, ntq = w >> 1;         // m-tile 0..1, n-tile 0..1 within quarter
    #pragma unroll 1
    for (int qq = 0; qq < 8; ++qq) {
        __syncthreads();
        stageW16(wsp + qq * 8192, lds, t);
        __syncthreads();
        f32x4 a = (f32x4){0.f, 0.f, 0.f, 0.f};
        #pragma unroll
        for (int kc = 0; kc < 8; ++kc) {
            short8 af = frag(lds, O_XA, 16 * mt + lm, kc * 32 + lg * 8, 256);
            short8 bf = frag(lds, O_WB, 16 * ntq + lm, kc * 32 + lg * 8, 256);
            a = __builtin_amdgcn_mfma_f32_16x16x32_bf16(af, bf, a, 0, 0, 0);
        }
        int o = (qq & 3) * 32 + 16 * ntq + lm;
        if (qq < 4) {
            float bb = bk[o];
            #pragma unroll
            for (int r = 0; r < 4; ++r) {
                int tok = 16 * mt + 4 * lg + r;     // 0..31
                lds[O_K + tok * 128 + ((((o >> 1) ^ tok) << 1) | (o & 1))] =
                    (unsigned short)bf16r(a[r] + bb);
            }
        } else {
            float bb = bv[o];
            #pragma unroll
            for (int r = 0; r < 4; ++r) {
                int tok = 16 * mt + 4 * lg + r;
                lds[O_V + tok * 128 + (o ^ ((tok & 7) << 3))] =
                    (unsigned short)bf16r(a[r] + bb);
            }
        }
    }

    // ---- pass 1: Q GEMM + item-loop logits/DANE ----
    float lgr0[2], lgr1[2];
    float sdacc[2] = {0.f, 0.f};
    PASS1_DY(0, lgr0);
    PASS1_DY(1, lgr1);
    __syncthreads();

    // write logits (bf16) + sm (f32)
    #pragma unroll
    for (int ii = 0; ii < 2; ++ii) {
        int h = hgrp + 4 * ii;
        lds[O_LG + irow * 8 + (h ^ (irow & 7))]       = (unsigned short)bf16r(lgr0[ii]);
        lds[O_LG + 512 + irow * 8 + (h ^ (irow & 7))] = (unsigned short)bf16r(lgr1[ii]);
        float sdt = sdacc[ii] + __shfl_xor(sdacc[ii], 1, 64);
        if ((t & 1) == 0) smk[(irow >> 1) * 8 + h] = sdt * 0.25f;
    }
    __syncthreads();

    // ---- softmax over 4 px per (jj, h): 256 items, one per thread ----
    {
        int jj = t >> 3, h = t & 7;
        int ra = 2 * jj, rb2 = 2 * jj + 1;
        int a0 = ra * 8 + (h ^ (ra & 7));
        int a1 = rb2 * 8 + (h ^ (rb2 & 7));
        int a2 = 512 + a0;
        int a3 = 512 + a1;
        float l0 = ubf(lds[O_LG + a0]), l1 = ubf(lds[O_LG + a1]);
        float l2 = ubf(lds[O_LG + a2]), l3 = ubf(lds[O_LG + a3]);
        float mx = fmaxf(fmaxf(l0, l1), fmaxf(l2, l3));
        float e0 = __expf(l0 - mx), e1 = __expf(l1 - mx);
        float e2 = __expf(l2 - mx), e3 = __expf(l3 - mx);
        float inv = 1.f / (e0 + e1 + e2 + e3);
        lds[O_LG + a0] = (unsigned short)bf16r(e0 * inv);
        lds[O_LG + a1] = (unsigned short)bf16r(e1 * inv);
        lds[O_LG + a2] = (unsigned short)bf16r(e2 * inv);
        lds[O_LG + a3] = (unsigned short)bf16r(e3 * inv);
    }

    // ---- pass 2 per dy: VQ -> combine -> P -> LN -> store ----
    #pragma unroll 1
    for (int dy = 0; dy < 2; ++dy) {
        __syncthreads();
        stageA16<64, 128>(hb0 + dy * 256, 65536, lds, O_XA, t);
        stageW16(wsp + 81920, lds, t);          // WQV half 0
        __syncthreads();
        f32x4 vA[4], vB[4];
        ZERO4(vA); GEMM4(vA);
        __syncthreads();
        stageW16(wsp + 81920 + 8192, lds, t);   // WQV half 1
        __syncthreads();
        ZERO4(vB); GEMM4(vB);
        __syncthreads();                        // VQ reads of XA done
        COMBINE(vA, dy, 0);
        COMBINE(vB, dy, 1);
        stageW16(wsp + 98304, lds, t);          // WP half 0
        __syncthreads();                        // xc + WP visible

        f32x4 pA[4], pB[4];
        ZERO4(pA); GEMM4(pA);
        __syncthreads();
        stageW16(wsp + 98304 + 8192, lds, t);   // WP half 1
        __syncthreads();
        ZERO4(pB); GEMM4(pB);
        __syncthreads();                        // P reads of XA done

        LN_YN(pA, pB);
        __syncthreads();
        // coalesced store + residual (global, L2-hot)
        {
            const float* rb = hb0 + dy * 256;
            float* ob = out + (size_t)s * 33554432
                      + ((size_t)(b * 128)) * 65536 + (size_t)(2 * i0 + dy) * 256 + 2 * j0;
            int ph = t & 63, cq = t >> 6;
            #pragma unroll
            for (int it2 = 0; it2 < 16; ++it2) {
                int c4 = it2 * 4 + cq;
                unsigned uv = *(const unsigned*)&lds[O_XA + ph * 128 + ((c4 ^ (ph & 31)) << 1)];
                size_t off0 = (size_t)(2 * c4) * 65536 + ph;
                size_t off1 = off0 + 65536;
                ob[off0] = rb[off0] + ulo(uv);
                ob[off1] = rb[off1] + uhi(uv);
            }
        }
    }
}

extern "C" void kernel_launch(void* const* d_in, const int* in_sizes, int n_in,
                              void* d_out, int out_size, void* d_ws, size_t ws_size,
                              hipStream_t stream) {
    const float* x_l   = (const float*)d_in[0];
    const float* x_r   = (const float*)d_in[1];
    const float* x_lh  = (const float*)d_in[2];
    const float* x_rh  = (const float*)d_in[3];
    const float* Wq    = (const float*)d_in[4];
    const float* bq    = (const float*)d_in[5];
    const float* Wqv   = (const float*)d_in[6];
    const float* bqv   = (const float*)d_in[7];
    const float* Wk    = (const float*)d_in[8];
    const float* bk    = (const float*)d_in[9];
    const float* Wv    = (const float*)d_in[10];
    const float* bv    = (const float*)d_in[11];
    const float* Wp    = (const float*)d_in[12];
    const float* bp    = (const float*)d_in[13];
    const float* ln_g  = (const float*)d_in[14];
    const float* ln_b  = (const float*)d_in[15];
    const float* dln1g = (const float*)d_in[16];
    const float* dln1b = (const float*)d_in[17];
    const float* d_wsv = (const float*)d_in[18];
    const float* d_w1  = (const float*)d_in[19];
    const float* dln2g = (const float*)d_in[20];
    const float* dln2b = (const float*)d_in[21];
    const float* d_w2  = (const float*)d_in[22];

    float* out = (float*)d_out;
    float* ws_mean = (float*)d_ws;                                 // 2048 f
    float* ws_cm   = ws_mean + 2048;                               // 1024 f
    unsigned short* wsp = (unsigned short*)((char*)d_ws + 16384);  // 224 KB bf16 pool

    mean_kernel<<<2048, 256, 0, stream>>>(x_l, x_r, ws_mean);
    wprep<<<112, 256, 0, stream>>>(Wq, Wqv, Wk, Wv, Wp, wsp);
    cm_kernel<<<8, 128, 0, stream>>>(ws_mean, ws_cm, Wk, bk, d_w1, dln2g, dln2b, d_w2);
    pafm_v10<<<4096, 256, 0, stream>>>(x_l, x_r, x_lh, x_rh,
                                       bq, bqv, bk, bv, bp, ln_g, ln_b,
                                       dln1g, dln1b, d_wsv, ws_cm, wsp, out);
}

// Round 17
// 875.633 us; speedup vs baseline: 1.7411x; 1.2760x over previous
//
#include <hip/hip_runtime.h>
#include <hip/hip_bf16.h>
#include <math.h>

// PAFM fused v11: v10 (32-patch blocks, 51KB LDS) with launch_bounds(256,2) —
// restores the 128-VGPR natural allocation (v10's (256,3) forced 84 -> spill).
// HW occupancy follows ACTUAL regs: expect 3 blocks/CU via LDS, no spill.
// Inputs fp32 dict order; output fp32. Grid 4096 x 256.

typedef short short8 __attribute__((ext_vector_type(8)));
typedef float f32x4 __attribute__((ext_vector_type(4)));
typedef unsigned uint4v __attribute__((ext_vector_type(4)));

__device__ __forceinline__ unsigned bf16r(float x) {
    unsigned u = __float_as_uint(x);
    return (u + 0x7FFFu + ((u >> 16) & 1u)) >> 16;
}
__device__ __forceinline__ unsigned pack2(float a, float b) {
    return bf16r(a) | (bf16r(b) << 16);
}
__device__ __forceinline__ float ubf(unsigned short h) {
    return __uint_as_float(((unsigned)h) << 16);
}
__device__ __forceinline__ float ulo(unsigned u) { return __uint_as_float(u << 16); }
__device__ __forceinline__ float uhi(unsigned u) { return __uint_as_float(u & 0xFFFF0000u); }

// ---------------- kernel 1: per-(side,b,channel) spatial mean of x_low ----------------
__global__ __launch_bounds__(256) void mean_kernel(const float* __restrict__ x_l,
                                                   const float* __restrict__ x_r,
                                                   float* __restrict__ ws_mean) {
    int bid = blockIdx.x;
    const float* src = (bid >= 1024) ? x_r : x_l;
    const float* p = src + (size_t)(bid & 1023) * 16384;
    int t = threadIdx.x;
    float acc = 0.f;
    #pragma unroll 4
    for (int i = t; i < 16384; i += 256) acc += p[i];
    #pragma unroll
    for (int off = 32; off > 0; off >>= 1) acc += __shfl_down(acc, off, 64);
    __shared__ float red[4];
    if ((t & 63) == 0) red[t >> 6] = acc;
    __syncthreads();
    if (t == 0) ws_mean[bid] = (red[0] + red[1] + red[2] + red[3]) * (1.f / 16384.f);
}

// ---------------- kernel 2: channel gate cm[side][b][128] ----------------
__global__ __launch_bounds__(128) void cm_kernel(const float* __restrict__ ws_mean,
                                                 float* __restrict__ ws_cm,
                                                 const float* __restrict__ Wk,
                                                 const float* __restrict__ bk,
                                                 const float* __restrict__ d_w1,
                                                 const float* __restrict__ d_ln2_g,
                                                 const float* __restrict__ d_ln2_b,
                                                 const float* __restrict__ d_w2) {
    int sb = blockIdx.x;
    __shared__ float km[128];
    int o = threadIdx.x;
    const float* mu = ws_mean + sb * 256;
    float acc = bk[o];
    for (int c = 0; c < 256; ++c) acc = fmaf(Wk[o * 256 + c], mu[c], acc);
    km[o] = acc;
    __syncthreads();
    int h = o >> 4, d = o & 15;
    float t1[8];
    #pragma unroll
    for (int r = 0; r < 8; ++r) {
        float a = 0.f;
        #pragma unroll
        for (int dd = 0; dd < 16; ++dd) a = fmaf(d_w1[r * 16 + dd], km[h * 16 + dd], a);
        t1[r] = a / (1.f + expf(-a));
    }
    float m = 0.f;
    #pragma unroll
    for (int r = 0; r < 8; ++r) m += t1[r];
    m *= 0.125f;
    float v = 0.f;
    #pragma unroll
    for (int r = 0; r < 8; ++r) { float df = t1[r] - m; v = fmaf(df, df, v); }
    float rstd = rsqrtf(v * 0.125f + 1e-5f);
    float cmv = 0.f;
    #pragma unroll
    for (int r = 0; r < 8; ++r)
        cmv = fmaf((t1[r] - m) * rstd * d_ln2_g[r] + d_ln2_b[r], d_w2[d * 8 + r], cmv);
    ws_cm[sb * 128 + o] = cmv;
}

// ---------------- kernel 2b: weights -> bf16 pre-swizzled pool in ws ----------------
// pool (u16): WK=0 [4][32][256]; WV=32768; WQ=65536 [2][64][128]; WQV=81920; WP=98304
__global__ __launch_bounds__(256) void wprep(const float* __restrict__ Wq,
                                             const float* __restrict__ Wqv,
                                             const float* __restrict__ Wk,
                                             const float* __restrict__ Wv,
                                             const float* __restrict__ Wp,
                                             unsigned short* __restrict__ wsp) {
    int bid = blockIdx.x, t = threadIdx.x;
    if (bid < 64) {
        const float* src = (bid < 32) ? Wk : Wv;
        unsigned short* dst = wsp + ((bid < 32) ? 0 : 32768);
        int base = (bid & 31) * 1024;
        #pragma unroll
        for (int i = 0; i < 4; ++i) {
            int el = base + t + 256 * i;
            int q = el >> 13, rem = el & 8191, op = rem >> 8, col = rem & 255;
            dst[q * 8192 + op * 256 + (col ^ ((op & 7) << 3))] =
                (unsigned short)bf16r(src[(q * 32 + op) * 256 + col]);
        }
    } else {
        int g = (bid - 64) >> 4;
        const float* src = (g == 0) ? Wq : (g == 1) ? Wqv : Wp;
        unsigned short* dst = wsp + 65536 + g * 16384;
        int base = ((bid - 64) & 15) * 1024;
        #pragma unroll
        for (int i = 0; i < 4; ++i) {
            int el = base + t + 256 * i;
            int hf = el >> 13, rem = el & 8191, op = rem >> 7, col = rem & 127;
            dst[hf * 8192 + op * 128 + (col ^ ((op & 7) << 3))] =
                (unsigned short)bf16r(src[(hf * 64 + op) * 128 + col]);
        }
    }
}

// LDS offsets (u16) — total 26112 u16 = 51 KB (3 blocks/CU)
#define O_XA 0       // 8192: x_low[32][256] / x_high[64][128] / Q-dump / xc / yn
#define O_WB 8192    // 8192: weight stage
#define O_K  16384   // 4096: K[32][128] u32-pair swizzle
#define O_V  20480   // 4096: V[32][128] frag swizzle
#define O_LG 24576   // 1024: logits/aw [2 dy][64 rows][8 heads]
#define O_SM 25600   // 512 u16 = 256 f32: sm[32][8]
#define LDS_U16 26112

__device__ __forceinline__ short8 frag(const unsigned short* lds, int off, int row, int k, int C2) {
    return *(const short8*)&lds[off + row * C2 + (k ^ ((row & 7) << 3))];
}

// stage fp32 activation tile -> bf16 LDS, frag-swizzled, 16B/lane writes
template<int R, int C2>
__device__ __forceinline__ void stageA16(const float* __restrict__ g, size_t cstride,
                                         unsigned short* lds, int off, int t) {
    #pragma unroll
    for (int it = 0; it < (R * (C2 / 8)) / 256; ++it) {
        int idx = t + it * 256;
        int rr = idx & (R - 1);
        int bc = idx / R;
        float v0 = g[(size_t)(8 * bc + 0) * cstride + rr];
        float v1 = g[(size_t)(8 * bc + 1) * cstride + rr];
        float v2 = g[(size_t)(8 * bc + 2) * cstride + rr];
        float v3 = g[(size_t)(8 * bc + 3) * cstride + rr];
        float v4 = g[(size_t)(8 * bc + 4) * cstride + rr];
        float v5 = g[(size_t)(8 * bc + 5) * cstride + rr];
        float v6 = g[(size_t)(8 * bc + 6) * cstride + rr];
        float v7 = g[(size_t)(8 * bc + 7) * cstride + rr];
        uint4v u = {pack2(v0, v1), pack2(v2, v3), pack2(v4, v5), pack2(v6, v7)};
        *(uint4v*)&lds[off + rr * C2 + ((bc ^ (rr & 7)) << 3)] = u;
    }
}

// linear 16KB (8192 u16) copy of pre-swizzled bf16 weights into WB
__device__ __forceinline__ void stageW16(const unsigned short* __restrict__ src,
                                         unsigned short* lds, int t) {
    #pragma unroll
    for (int c = 0; c < 4; ++c) {
        int u = (c * 256 + t) * 8;
        *(short8*)&lds[O_WB + u] = *(const short8*)&src[u];
    }
}

#define ZERO4(A) do { _Pragma("unroll") for (int z_ = 0; z_ < 4; ++z_) A[z_] = (f32x4){0.f,0.f,0.f,0.f}; } while (0)

// one m-tile (w) x 4 n-tiles over 128-col A (XA, 64 rows) / B (WB, 64 rows)
#define GEMM4(ACC) do {                                                            \
    _Pragma("unroll")                                                              \
    for (int kc_ = 0; kc_ < 4; ++kc_) {                                            \
      short8 af_ = frag(lds, O_XA, 16 * w + lm, kc_ * 32 + lg * 8, 128);           \
      _Pragma("unroll")                                                            \
      for (int n_ = 0; n_ < 4; ++n_) {                                             \
        short8 bf_ = frag(lds, O_WB, 16 * n_ + lm, kc_ * 32 + lg * 8, 128);        \
        ACC[n_] = __builtin_amdgcn_mfma_f32_16x16x32_bf16(af_, bf_, ACC[n_], 0, 0, 0); \
      } }                                                                          \
  } while (0)

#define QDUMP(ACC, OBASE) do {                                                     \
    _Pragma("unroll")                                                              \
    for (int n_ = 0; n_ < 4; ++n_) {                                               \
      int o_ = (OBASE) + 16 * n_ + lm;                                             \
      float bb_ = bq[o_];                                                          \
      _Pragma("unroll")                                                            \
      for (int r_ = 0; r_ < 4; ++r_) {                                             \
        int row_ = 16 * w + 4 * lg + r_;                                           \
        lds[O_XA + row_ * 128 + ((((o_ >> 1) ^ (row_ & 31)) << 1) | (o_ & 1))] =   \
            (unsigned short)bf16r(ACC[n_][r_] + bb_);                              \
      } } } while (0)

#define COMBINE(ACC, DY, NH) do {                                                  \
    _Pragma("unroll")                                                              \
    for (int n_ = 0; n_ < 4; ++n_) {                                               \
      int nt_ = 4 * (NH) + n_;                                                     \
      int o_ = 16 * nt_ + lm;                                                      \
      float bias_ = bqv[o_];                                                       \
      float cmv_ = cmp[o_];                                                        \
      _Pragma("unroll")                                                            \
      for (int r_ = 0; r_ < 4; ++r_) {                                             \
        int row_ = 16 * w + 4 * lg + r_;                                           \
        int jj_ = row_ >> 1;                                                       \
        float vq_ = ACC[n_][r_] + bias_;                                           \
        float aw_ = ubf(lds[O_LG + (DY) * 512 + row_ * 8 + (nt_ ^ (row_ & 7))]);   \
        float vv_ = ubf(lds[O_V + jj_ * 128 + (o_ ^ ((jj_ & 7) << 3))]);           \
        float wg_ = 1.f / (1.f + __expf(-(smk[jj_ * 8 + nt_] + cmv_)));            \
        float xc_ = (1.f - wg_) * aw_ * vv_ * 4.f + wg_ * vq_;                     \
        lds[O_XA + row_ * 128 + (o_ ^ ((row_ & 7) << 3))] = (unsigned short)bf16r(xc_); \
      } } } while (0)

#define LN_YN(PA, PB) do {                                                         \
    _Pragma("unroll")                                                              \
    for (int r_ = 0; r_ < 4; ++r_) {                                               \
      float ps_ = 0.f, pq_ = 0.f;                                                  \
      _Pragma("unroll")                                                            \
      for (int n_ = 0; n_ < 4; ++n_) {                                             \
        float y0_ = PA[n_][r_] + bp[16 * n_ + lm];                                 \
        float y1_ = PB[n_][r_] + bp[64 + 16 * n_ + lm];                            \
        ps_ += y0_ + y1_;                                                          \
        pq_ = fmaf(y0_, y0_, fmaf(y1_, y1_, pq_));                                 \
      }                                                                            \
      _Pragma("unroll")                                                            \
      for (int d_ = 1; d_ < 16; d_ <<= 1) {                                        \
        ps_ += __shfl_xor(ps_, d_, 64); pq_ += __shfl_xor(pq_, d_, 64);            \
      }                                                                            \
      float mn_ = ps_ * (1.f / 128.f);                                             \
      float rs_ = rsqrtf(pq_ * (1.f / 128.f) - mn_ * mn_ + 1e-5f);                 \
      int row_ = 16 * w + 4 * lg + r_;                                             \
      _Pragma("unroll")                                                            \
      for (int n_ = 0; n_ < 4; ++n_) {                                             \
        int oA_ = 16 * n_ + lm, oB_ = 64 + 16 * n_ + lm;                           \
        float ynA_ = (PA[n_][r_] + bp[oA_] - mn_) * rs_ * ln_g[oA_] + ln_b[oA_];   \
        float ynB_ = (PB[n_][r_] + bp[oB_] - mn_) * rs_ * ln_g[oB_] + ln_b[oB_];   \
        lds[O_XA + row_ * 128 + ((((oA_ >> 1) ^ (row_ & 31)) << 1) | (oA_ & 1))] = (unsigned short)bf16r(ynA_); \
        lds[O_XA + row_ * 128 + ((((oB_ >> 1) ^ (row_ & 31)) << 1) | (oB_ & 1))] = (unsigned short)bf16r(ynB_); \
      }                                                                            \
    } } while (0)

// pass-1 per-dy body (DY literal, LGR = per-dy 2-logit register array)
#define PASS1_DY(DY, LGR) do {                                                     \
    __syncthreads();                                                               \
    stageA16<64, 128>(hb0 + (DY) * 256, 65536, lds, O_XA, t);                      \
    stageW16(wsp + 65536, lds, t);                                                 \
    __syncthreads();                                                               \
    f32x4 qA[4], qB[4];                                                            \
    ZERO4(qA); GEMM4(qA);                                                          \
    __syncthreads();                                                               \
    stageW16(wsp + 65536 + 8192, lds, t);                                          \
    __syncthreads();                                                               \
    ZERO4(qB); GEMM4(qB);                                                          \
    __syncthreads();                                                               \
    QDUMP(qA, 0); QDUMP(qB, 64);                                                   \
    __syncthreads();                                                               \
    _Pragma("unroll")                                                              \
    for (int ii = 0; ii < 2; ++ii) {                                               \
      int h_ = hgrp + 4 * ii;                                                      \
      int tok_ = irow >> 1;                                                        \
      float sq = 0.f, sqq = 0.f, sgw = 0.f, sqk = 0.f;                             \
      _Pragma("unroll")                                                            \
      for (int d2 = 0; d2 < 8; ++d2) {                                             \
        unsigned qu = *(const unsigned*)&lds[O_XA + irow * 128 + (((h_ * 8 + d2) ^ (irow & 31)) << 1)]; \
        unsigned ku = *(const unsigned*)&lds[O_K + tok_ * 128 + (((h_ * 8 + d2) ^ tok_) << 1)];         \
        float q0 = ulo(qu), q1 = uhi(qu);                                          \
        float k0 = ulo(ku), k1 = uhi(ku);                                          \
        sq += q0 + q1;                                                             \
        sqq = fmaf(q0, q0, fmaf(q1, q1, sqq));                                     \
        sgw = fmaf(q0, gwv[2 * d2], fmaf(q1, gwv[2 * d2 + 1], sgw));               \
        sqk = fmaf(q0, k0, fmaf(q1, k1, sqk));                                     \
      }                                                                            \
      LGR[ii] = sqk * 0.25f;                                                       \
      float mn_ = sq * 0.0625f;                                                    \
      float rs_ = rsqrtf(sqq * 0.0625f - mn_ * mn_ + 1e-5f);                       \
      sdacc[ii] += rs_ * (sgw - mn_ * S1) + S2;                                    \
    }                                                                              \
  } while (0)

// ---------------- kernel 3: fused main ----------------
__global__ __launch_bounds__(256, 2) void pafm_v11(
    const float* __restrict__ x_l,  const float* __restrict__ x_r,
    const float* __restrict__ x_lh, const float* __restrict__ x_rh,
    const float* __restrict__ bq,   const float* __restrict__ bqv,
    const float* __restrict__ bk,   const float* __restrict__ bv,
    const float* __restrict__ bp,
    const float* __restrict__ ln_g, const float* __restrict__ ln_b,
    const float* __restrict__ d_ln1_g, const float* __restrict__ d_ln1_b,
    const float* __restrict__ d_wsv,
    const float* __restrict__ ws_cm,
    const unsigned short* __restrict__ wsp,
    float* __restrict__ out) {

    __shared__ unsigned short lds[LDS_U16];
    float* smk = (float*)&lds[O_SM];      // sm f32[256]

    int bid = blockIdx.x;                 // s(1)|b(2)|i0(7)|jb(2)
    int s  = bid >> 11;
    int b  = (bid >> 9) & 3;
    int i0 = (bid >> 2) & 127;
    int j0 = (bid & 3) * 32;

    int t = threadIdx.x, w = t >> 6, l = t & 63, lm = l & 15, lg = l >> 4;
    int irow = t & 63, hgrp = t >> 6;

    const float* xlow  = s ? x_r  : x_l;
    const float* xhigh = s ? x_rh : x_lh;
    const float* cmp   = ws_cm + (s * 4 + b) * 128;

    // DANE coefficients
    float gwv[16], S1 = 0.f, S2 = 0.f;
    #pragma unroll
    for (int d = 0; d < 16; ++d) {
        float wsd = d_wsv[d];
        gwv[d] = d_ln1_g[d] * wsd;
        S1 += gwv[d];
        S2 += d_ln1_b[d] * wsd;
    }

    const float* lowb = xlow + ((size_t)(b * 256) * 128 + i0) * 128 + j0;
    const float* hb0  = xhigh + ((size_t)(b * 128) * 256 + 2 * i0) * 256 + 2 * j0;

    // ---- KV phase: x_low[32][256] staged once; 8 weight quarters (4 Wk + 4 Wv) ----
    stageA16<32, 256>(lowb, 16384, lds, O_XA, t);
    int mt = w & 1, ntq = w >> 1;         // m-tile 0..1, n-tile 0..1 within quarter
    #pragma unroll 1
    for (int qq = 0; qq < 8; ++qq) {
        __syncthreads();
        stageW16(wsp + qq * 8192, lds, t);
        __syncthreads();
        f32x4 a = (f32x4){0.f, 0.f, 0.f, 0.f};
        #pragma unroll
        for (int kc = 0; kc < 8; ++kc) {
            short8 af = frag(lds, O_XA, 16 * mt + lm, kc * 32 + lg * 8, 256);
            short8 bf = frag(lds, O_WB, 16 * ntq + lm, kc * 32 + lg * 8, 256);
            a = __builtin_amdgcn_mfma_f32_16x16x32_bf16(af, bf, a, 0, 0, 0);
        }
        int o = (qq & 3) * 32 + 16 * ntq + lm;
        if (qq < 4) {
            float bb = bk[o];
            #pragma unroll
            for (int r = 0; r < 4; ++r) {
                int tok = 16 * mt + 4 * lg + r;     // 0..31
                lds[O_K + tok * 128 + ((((o >> 1) ^ tok) << 1) | (o & 1))] =
                    (unsigned short)bf16r(a[r] + bb);
            }
        } else {
            float bb = bv[o];
            #pragma unroll
            for (int r = 0; r < 4; ++r) {
                int tok = 16 * mt + 4 * lg + r;
                lds[O_V + tok * 128 + (o ^ ((tok & 7) << 3))] =
                    (unsigned short)bf16r(a[r] + bb);
            }
        }
    }

    // ---- pass 1: Q GEMM + item-loop logits/DANE ----
    float lgr0[2], lgr1[2];
    float sdacc[2] = {0.f, 0.f};
    PASS1_DY(0, lgr0);
    PASS1_DY(1, lgr1);
    __syncthreads();

    // write logits (bf16) + sm (f32)
    #pragma unroll
    for (int ii = 0; ii < 2; ++ii) {
        int h = hgrp + 4 * ii;
        lds[O_LG + irow * 8 + (h ^ (irow & 7))]       = (unsigned short)bf16r(lgr0[ii]);
        lds[O_LG + 512 + irow * 8 + (h ^ (irow & 7))] = (unsigned short)bf16r(lgr1[ii]);
        float sdt = sdacc[ii] + __shfl_xor(sdacc[ii], 1, 64);
        if ((t & 1) == 0) smk[(irow >> 1) * 8 + h] = sdt * 0.25f;
    }
    __syncthreads();

    // ---- softmax over 4 px per (jj, h): 256 items, one per thread ----
    {
        int jj = t >> 3, h = t & 7;
        int ra = 2 * jj, rb2 = 2 * jj + 1;
        int a0 = ra * 8 + (h ^ (ra & 7));
        int a1 = rb2 * 8 + (h ^ (rb2 & 7));
        int a2 = 512 + a0;
        int a3 = 512 + a1;
        float l0 = ubf(lds[O_LG + a0]), l1 = ubf(lds[O_LG + a1]);
        float l2 = ubf(lds[O_LG + a2]), l3 = ubf(lds[O_LG + a3]);
        float mx = fmaxf(fmaxf(l0, l1), fmaxf(l2, l3));
        float e0 = __expf(l0 - mx), e1 = __expf(l1 - mx);
        float e2 = __expf(l2 - mx), e3 = __expf(l3 - mx);
        float inv = 1.f / (e0 + e1 + e2 + e3);
        lds[O_LG + a0] = (unsigned short)bf16r(e0 * inv);
        lds[O_LG + a1] = (unsigned short)bf16r(e1 * inv);
        lds[O_LG + a2] = (unsigned short)bf16r(e2 * inv);
        lds[O_LG + a3] = (unsigned short)bf16r(e3 * inv);
    }

    // ---- pass 2 per dy: VQ -> combine -> P -> LN -> store ----
    #pragma unroll 1
    for (int dy = 0; dy < 2; ++dy) {
        __syncthreads();
        stageA16<64, 128>(hb0 + dy * 256, 65536, lds, O_XA, t);
        stageW16(wsp + 81920, lds, t);          // WQV half 0
        __syncthreads();
        f32x4 vA[4], vB[4];
        ZERO4(vA); GEMM4(vA);
        __syncthreads();
        stageW16(wsp + 81920 + 8192, lds, t);   // WQV half 1
        __syncthreads();
        ZERO4(vB); GEMM4(vB);
        __syncthreads();                        // VQ reads of XA done
        COMBINE(vA, dy, 0);
        COMBINE(vB, dy, 1);
        stageW16(wsp + 98304, lds, t);          // WP half 0
        __syncthreads();                        // xc + WP visible

        f32x4 pA[4], pB[4];
        ZERO4(pA); GEMM4(pA);
        __syncthreads();
        stageW16(wsp + 98304 + 8192, lds, t);   // WP half 1
        __syncthreads();
        ZERO4(pB); GEMM4(pB);
        __syncthreads();                        // P reads of XA done

        LN_YN(pA, pB);
        __syncthreads();
        // coalesced store + residual (global, L2-hot)
        {
            const float* rb = hb0 + dy * 256;
            float* ob = out + (size_t)s * 33554432
                      + ((size_t)(b * 128)) * 65536 + (size_t)(2 * i0 + dy) * 256 + 2 * j0;
            int ph = t & 63, cq = t >> 6;
            #pragma unroll
            for (int it2 = 0; it2 < 16; ++it2) {
                int c4 = it2 * 4 + cq;
                unsigned uv = *(const unsigned*)&lds[O_XA + ph * 128 + ((c4 ^ (ph & 31)) << 1)];
                size_t off0 = (size_t)(2 * c4) * 65536 + ph;
                size_t off1 = off0 + 65536;
                ob[off0] = rb[off0] + ulo(uv);
                ob[off1] = rb[off1] + uhi(uv);
            }
        }
    }
}

extern "C" void kernel_launch(void* const* d_in, const int* in_sizes, int n_in,
                              void* d_out, int out_size, void* d_ws, size_t ws_size,
                              hipStream_t stream) {
    const float* x_l   = (const float*)d_in[0];
    const float* x_r   = (const float*)d_in[1];
    const float* x_lh  = (const float*)d_in[2];
    const float* x_rh  = (const float*)d_in[3];
    const float* Wq    = (const float*)d_in[4];
    const float* bq    = (const float*)d_in[5];
    const float* Wqv   = (const float*)d_in[6];
    const float* bqv   = (const float*)d_in[7];
    const float* Wk    = (const float*)d_in[8];
    const float* bk    = (const float*)d_in[9];
    const float* Wv    = (const float*)d_in[10];
    const float* bv    = (const float*)d_in[11];
    const float* Wp    = (const float*)d_in[12];
    const float* bp    = (const float*)d_in[13];
    const float* ln_g  = (const float*)d_in[14];
    const float* ln_b  = (const float*)d_in[15];
    const float* dln1g = (const float*)d_in[16];
    const float* dln1b = (const float*)d_in[17];
    const float* d_wsv = (const float*)d_in[18];
    const float* d_w1  = (const float*)d_in[19];
    const float* dln2g = (const float*)d_in[20];
    const float* dln2b = (const float*)d_in[21];
    const float* d_w2  = (const float*)d_in[22];

    float* out = (float*)d_out;
    float* ws_mean = (float*)d_ws;                                 // 2048 f
    float* ws_cm   = ws_mean + 2048;                               // 1024 f
    unsigned short* wsp = (unsigned short*)((char*)d_ws + 16384);  // 224 KB bf16 pool

    mean_kernel<<<2048, 256, 0, stream>>>(x_l, x_r, ws_mean);
    wprep<<<112, 256, 0, stream>>>(Wq, Wqv, Wk, Wv, Wp, wsp);
    cm_kernel<<<8, 128, 0, stream>>>(ws_mean, ws_cm, Wk, bk, d_w1, dln2g, dln2b, d_w2);
    pafm_v11<<<4096, 256, 0, stream>>>(x_l, x_r, x_lh, x_rh,
                                       bq, bqv, bk, bv, bp, ln_g, ln_b,
                                       dln1g, dln1b, d_wsv, ws_cm, wsp, out);
}

// Round 18
// 854.790 us; speedup vs baseline: 1.7835x; 1.0244x over previous
//
#include <hip/hip_runtime.h>
#include <hip/hip_bf16.h>
#include <math.h>

// PAFM fused v12: v11 math, re-scheduled: ping-pong weight buffers (WB0/WB1),
// merged GEMM halves, staging overlapped with compute. 67KB LDS, 2 blocks/CU.
// Inputs fp32 dict order; output fp32. Grid 4096 x 256.

typedef short short8 __attribute__((ext_vector_type(8)));
typedef float f32x4 __attribute__((ext_vector_type(4)));
typedef unsigned uint4v __attribute__((ext_vector_type(4)));

__device__ __forceinline__ unsigned bf16r(float x) {
    unsigned u = __float_as_uint(x);
    return (u + 0x7FFFu + ((u >> 16) & 1u)) >> 16;
}
__device__ __forceinline__ unsigned pack2(float a, float b) {
    return bf16r(a) | (bf16r(b) << 16);
}
__device__ __forceinline__ float ubf(unsigned short h) {
    return __uint_as_float(((unsigned)h) << 16);
}
__device__ __forceinline__ float ulo(unsigned u) { return __uint_as_float(u << 16); }
__device__ __forceinline__ float uhi(unsigned u) { return __uint_as_float(u & 0xFFFF0000u); }

// ---------------- kernel 1: per-(side,b,channel) spatial mean of x_low ----------------
__global__ __launch_bounds__(256) void mean_kernel(const float* __restrict__ x_l,
                                                   const float* __restrict__ x_r,
                                                   float* __restrict__ ws_mean) {
    int bid = blockIdx.x;
    const float* src = (bid >= 1024) ? x_r : x_l;
    const float* p = src + (size_t)(bid & 1023) * 16384;
    int t = threadIdx.x;
    float acc = 0.f;
    #pragma unroll 4
    for (int i = t; i < 16384; i += 256) acc += p[i];
    #pragma unroll
    for (int off = 32; off > 0; off >>= 1) acc += __shfl_down(acc, off, 64);
    __shared__ float red[4];
    if ((t & 63) == 0) red[t >> 6] = acc;
    __syncthreads();
    if (t == 0) ws_mean[bid] = (red[0] + red[1] + red[2] + red[3]) * (1.f / 16384.f);
}

// ---------------- kernel 2: channel gate cm[side][b][128] ----------------
__global__ __launch_bounds__(128) void cm_kernel(const float* __restrict__ ws_mean,
                                                 float* __restrict__ ws_cm,
                                                 const float* __restrict__ Wk,
                                                 const float* __restrict__ bk,
                                                 const float* __restrict__ d_w1,
                                                 const float* __restrict__ d_ln2_g,
                                                 const float* __restrict__ d_ln2_b,
                                                 const float* __restrict__ d_w2) {
    int sb = blockIdx.x;
    __shared__ float km[128];
    int o = threadIdx.x;
    const float* mu = ws_mean + sb * 256;
    float acc = bk[o];
    for (int c = 0; c < 256; ++c) acc = fmaf(Wk[o * 256 + c], mu[c], acc);
    km[o] = acc;
    __syncthreads();
    int h = o >> 4, d = o & 15;
    float t1[8];
    #pragma unroll
    for (int r = 0; r < 8; ++r) {
        float a = 0.f;
        #pragma unroll
        for (int dd = 0; dd < 16; ++dd) a = fmaf(d_w1[r * 16 + dd], km[h * 16 + dd], a);
        t1[r] = a / (1.f + expf(-a));
    }
    float m = 0.f;
    #pragma unroll
    for (int r = 0; r < 8; ++r) m += t1[r];
    m *= 0.125f;
    float v = 0.f;
    #pragma unroll
    for (int r = 0; r < 8; ++r) { float df = t1[r] - m; v = fmaf(df, df, v); }
    float rstd = rsqrtf(v * 0.125f + 1e-5f);
    float cmv = 0.f;
    #pragma unroll
    for (int r = 0; r < 8; ++r)
        cmv = fmaf((t1[r] - m) * rstd * d_ln2_g[r] + d_ln2_b[r], d_w2[d * 8 + r], cmv);
    ws_cm[sb * 128 + o] = cmv;
}

// ---------------- kernel 2b: weights -> bf16 pre-swizzled pool in ws ----------------
// pool (u16): WK=0 [4][32][256]; WV=32768; WQ=65536 [2][64][128]; WQV=81920; WP=98304
__global__ __launch_bounds__(256) void wprep(const float* __restrict__ Wq,
                                             const float* __restrict__ Wqv,
                                             const float* __restrict__ Wk,
                                             const float* __restrict__ Wv,
                                             const float* __restrict__ Wp,
                                             unsigned short* __restrict__ wsp) {
    int bid = blockIdx.x, t = threadIdx.x;
    if (bid < 64) {
        const float* src = (bid < 32) ? Wk : Wv;
        unsigned short* dst = wsp + ((bid < 32) ? 0 : 32768);
        int base = (bid & 31) * 1024;
        #pragma unroll
        for (int i = 0; i < 4; ++i) {
            int el = base + t + 256 * i;
            int q = el >> 13, rem = el & 8191, op = rem >> 8, col = rem & 255;
            dst[q * 8192 + op * 256 + (col ^ ((op & 7) << 3))] =
                (unsigned short)bf16r(src[(q * 32 + op) * 256 + col]);
        }
    } else {
        int g = (bid - 64) >> 4;
        const float* src = (g == 0) ? Wq : (g == 1) ? Wqv : Wp;
        unsigned short* dst = wsp + 65536 + g * 16384;
        int base = ((bid - 64) & 15) * 1024;
        #pragma unroll
        for (int i = 0; i < 4; ++i) {
            int el = base + t + 256 * i;
            int hf = el >> 13, rem = el & 8191, op = rem >> 7, col = rem & 127;
            dst[hf * 8192 + op * 128 + (col ^ ((op & 7) << 3))] =
                (unsigned short)bf16r(src[(hf * 64 + op) * 128 + col]);
        }
    }
}

// LDS offsets (u16) — total 34304 u16 = 67 KB (2 blocks/CU)
#define O_XA  0      // 8192: x_low[32][256] / x_high[64][128] / Q-dump / xc / yn
#define O_WB0 8192   // 8192: weight stage buffer 0
#define O_WB1 16384  // 8192: weight stage buffer 1
#define O_K   24576  // 4096: K[32][128] u32-pair swizzle
#define O_V   28672  // 4096: V[32][128] frag swizzle
#define O_LG  32768  // 1024: logits/aw [2 dy][64 rows][8 heads]
#define O_SM  33792  // 512 u16 = 256 f32: sm[32][8]
#define LDS_U16 34304

__device__ __forceinline__ short8 frag(const unsigned short* lds, int off, int row, int k, int C2) {
    return *(const short8*)&lds[off + row * C2 + (k ^ ((row & 7) << 3))];
}

// stage fp32 activation tile -> bf16 LDS, frag-swizzled, 16B/lane writes
template<int R, int C2>
__device__ __forceinline__ void stageA16(const float* __restrict__ g, size_t cstride,
                                         unsigned short* lds, int off, int t) {
    #pragma unroll
    for (int it = 0; it < (R * (C2 / 8)) / 256; ++it) {
        int idx = t + it * 256;
        int rr = idx & (R - 1);
        int bc = idx / R;
        float v0 = g[(size_t)(8 * bc + 0) * cstride + rr];
        float v1 = g[(size_t)(8 * bc + 1) * cstride + rr];
        float v2 = g[(size_t)(8 * bc + 2) * cstride + rr];
        float v3 = g[(size_t)(8 * bc + 3) * cstride + rr];
        float v4 = g[(size_t)(8 * bc + 4) * cstride + rr];
        float v5 = g[(size_t)(8 * bc + 5) * cstride + rr];
        float v6 = g[(size_t)(8 * bc + 6) * cstride + rr];
        float v7 = g[(size_t)(8 * bc + 7) * cstride + rr];
        uint4v u = {pack2(v0, v1), pack2(v2, v3), pack2(v4, v5), pack2(v6, v7)};
        *(uint4v*)&lds[off + rr * C2 + ((bc ^ (rr & 7)) << 3)] = u;
    }
}

// linear 16KB (8192 u16) copy of pre-swizzled bf16 weights into WB[wboff]
__device__ __forceinline__ void stageW16(const unsigned short* __restrict__ src,
                                         unsigned short* lds, int wboff, int t) {
    #pragma unroll
    for (int c = 0; c < 4; ++c) {
        int u = (c * 256 + t) * 8;
        *(short8*)&lds[wboff + u] = *(const short8*)&src[u];
    }
}

#define ZERO4(A) do { _Pragma("unroll") for (int z_ = 0; z_ < 4; ++z_) A[z_] = (f32x4){0.f,0.f,0.f,0.f}; } while (0)

// one m-tile (w) x 4 n-tiles over 128-col A (XA, 64 rows) / B (WB at WBOFF)
#define GEMM4(ACC, WBOFF) do {                                                     \
    _Pragma("unroll")                                                              \
    for (int kc_ = 0; kc_ < 4; ++kc_) {                                            \
      short8 af_ = frag(lds, O_XA, 16 * w + lm, kc_ * 32 + lg * 8, 128);           \
      _Pragma("unroll")                                                            \
      for (int n_ = 0; n_ < 4; ++n_) {                                             \
        short8 bf_ = frag(lds, (WBOFF), 16 * n_ + lm, kc_ * 32 + lg * 8, 128);     \
        ACC[n_] = __builtin_amdgcn_mfma_f32_16x16x32_bf16(af_, bf_, ACC[n_], 0, 0, 0); \
      } }                                                                          \
  } while (0)

#define QDUMP(ACC, OBASE) do {                                                     \
    _Pragma("unroll")                                                              \
    for (int n_ = 0; n_ < 4; ++n_) {                                               \
      int o_ = (OBASE) + 16 * n_ + lm;                                             \
      float bb_ = bq[o_];                                                          \
      _Pragma("unroll")                                                            \
      for (int r_ = 0; r_ < 4; ++r_) {                                             \
        int row_ = 16 * w + 4 * lg + r_;                                           \
        lds[O_XA + row_ * 128 + ((((o_ >> 1) ^ (row_ & 31)) << 1) | (o_ & 1))] =   \
            (unsigned short)bf16r(ACC[n_][r_] + bb_);                              \
      } } } while (0)

#define COMBINE(ACC, DY, NH) do {                                                  \
    _Pragma("unroll")                                                              \
    for (int n_ = 0; n_ < 4; ++n_) {                                               \
      int nt_ = 4 * (NH) + n_;                                                     \
      int o_ = 16 * nt_ + lm;                                                      \
      float bias_ = bqv[o_];                                                       \
      float cmv_ = cmp[o_];                                                        \
      _Pragma("unroll")                                                            \
      for (int r_ = 0; r_ < 4; ++r_) {                                             \
        int row_ = 16 * w + 4 * lg + r_;                                           \
        int jj_ = row_ >> 1;                                                       \
        float vq_ = ACC[n_][r_] + bias_;                                           \
        float aw_ = ubf(lds[O_LG + (DY) * 512 + row_ * 8 + (nt_ ^ (row_ & 7))]);   \
        float vv_ = ubf(lds[O_V + jj_ * 128 + (o_ ^ ((jj_ & 7) << 3))]);           \
        float wg_ = 1.f / (1.f + __expf(-(smk[jj_ * 8 + nt_] + cmv_)));            \
        float xc_ = (1.f - wg_) * aw_ * vv_ * 4.f + wg_ * vq_;                     \
        lds[O_XA + row_ * 128 + (o_ ^ ((row_ & 7) << 3))] = (unsigned short)bf16r(xc_); \
      } } } while (0)

#define LN_YN(PA, PB) do {                                                         \
    _Pragma("unroll")                                                              \
    for (int r_ = 0; r_ < 4; ++r_) {                                               \
      float ps_ = 0.f, pq_ = 0.f;                                                  \
      _Pragma("unroll")                                                            \
      for (int n_ = 0; n_ < 4; ++n_) {                                             \
        float y0_ = PA[n_][r_] + bp[16 * n_ + lm];                                 \
        float y1_ = PB[n_][r_] + bp[64 + 16 * n_ + lm];                            \
        ps_ += y0_ + y1_;                                                          \
        pq_ = fmaf(y0_, y0_, fmaf(y1_, y1_, pq_));                                 \
      }                                                                            \
      _Pragma("unroll")                                                            \
      for (int d_ = 1; d_ < 16; d_ <<= 1) {                                        \
        ps_ += __shfl_xor(ps_, d_, 64); pq_ += __shfl_xor(pq_, d_, 64);            \
      }                                                                            \
      float mn_ = ps_ * (1.f / 128.f);                                             \
      float rs_ = rsqrtf(pq_ * (1.f / 128.f) - mn_ * mn_ + 1e-5f);                 \
      int row_ = 16 * w + 4 * lg + r_;                                             \
      _Pragma("unroll")                                                            \
      for (int n_ = 0; n_ < 4; ++n_) {                                             \
        int oA_ = 16 * n_ + lm, oB_ = 64 + 16 * n_ + lm;                           \
        float ynA_ = (PA[n_][r_] + bp[oA_] - mn_) * rs_ * ln_g[oA_] + ln_b[oA_];   \
        float ynB_ = (PB[n_][r_] + bp[oB_] - mn_) * rs_ * ln_g[oB_] + ln_b[oB_];   \
        lds[O_XA + row_ * 128 + ((((oA_ >> 1) ^ (row_ & 31)) << 1) | (oA_ & 1))] = (unsigned short)bf16r(ynA_); \
        lds[O_XA + row_ * 128 + ((((oB_ >> 1) ^ (row_ & 31)) << 1) | (oB_ & 1))] = (unsigned short)bf16r(ynB_); \
      }                                                                            \
    } } while (0)

// item-loop: logits + DANE for one dy (reads XA Q-dump + K region)
#define ITEMS(LGR) do {                                                            \
    _Pragma("unroll")                                                              \
    for (int ii = 0; ii < 2; ++ii) {                                               \
      int h_ = hgrp + 4 * ii;                                                      \
      int tok_ = irow >> 1;                                                        \
      float sq = 0.f, sqq = 0.f, sgw = 0.f, sqk = 0.f;                             \
      _Pragma("unroll")                                                            \
      for (int d2 = 0; d2 < 8; ++d2) {                                             \
        unsigned qu = *(const unsigned*)&lds[O_XA + irow * 128 + (((h_ * 8 + d2) ^ (irow & 31)) << 1)]; \
        unsigned ku = *(const unsigned*)&lds[O_K + tok_ * 128 + (((h_ * 8 + d2) ^ tok_) << 1)];         \
        float q0 = ulo(qu), q1 = uhi(qu);                                          \
        float k0 = ulo(ku), k1 = uhi(ku);                                          \
        sq += q0 + q1;                                                             \
        sqq = fmaf(q0, q0, fmaf(q1, q1, sqq));                                     \
        sgw = fmaf(q0, gwv[2 * d2], fmaf(q1, gwv[2 * d2 + 1], sgw));               \
        sqk = fmaf(q0, k0, fmaf(q1, k1, sqk));                                     \
      }                                                                            \
      LGR[ii] = sqk * 0.25f;                                                       \
      float mn_ = sq * 0.0625f;                                                    \
      float rs_ = rsqrtf(sqq * 0.0625f - mn_ * mn_ + 1e-5f);                       \
      sdacc[ii] += rs_ * (sgw - mn_ * S1) + S2;                                    \
    } } while (0)

// ---------------- kernel 3: fused main ----------------
__global__ __launch_bounds__(256, 2) void pafm_v12(
    const float* __restrict__ x_l,  const float* __restrict__ x_r,
    const float* __restrict__ x_lh, const float* __restrict__ x_rh,
    const float* __restrict__ bq,   const float* __restrict__ bqv,
    const float* __restrict__ bk,   const float* __restrict__ bv,
    const float* __restrict__ bp,
    const float* __restrict__ ln_g, const float* __restrict__ ln_b,
    const float* __restrict__ d_ln1_g, const float* __restrict__ d_ln1_b,
    const float* __restrict__ d_wsv,
    const float* __restrict__ ws_cm,
    const unsigned short* __restrict__ wsp,
    float* __restrict__ out) {

    __shared__ unsigned short lds[LDS_U16];
    float* smk = (float*)&lds[O_SM];      // sm f32[256]

    int bid = blockIdx.x;                 // s(1)|b(2)|i0(7)|jb(2)
    int s  = bid >> 11;
    int b  = (bid >> 9) & 3;
    int i0 = (bid >> 2) & 127;
    int j0 = (bid & 3) * 32;

    int t = threadIdx.x, w = t >> 6, l = t & 63, lm = l & 15, lg = l >> 4;
    int irow = t & 63, hgrp = t >> 6;

    const float* xlow  = s ? x_r  : x_l;
    const float* xhigh = s ? x_rh : x_lh;
    const float* cmp   = ws_cm + (s * 4 + b) * 128;

    // DANE coefficients
    float gwv[16], S1 = 0.f, S2 = 0.f;
    #pragma unroll
    for (int d = 0; d < 16; ++d) {
        float wsd = d_wsv[d];
        gwv[d] = d_ln1_g[d] * wsd;
        S1 += gwv[d];
        S2 += d_ln1_b[d] * wsd;
    }

    const float* lowb = xlow + ((size_t)(b * 256) * 128 + i0) * 128 + j0;
    const float* hb0  = xhigh + ((size_t)(b * 128) * 256 + 2 * i0) * 256 + 2 * j0;

    // ---- prologue: x_low + first weight quarter ----
    stageA16<32, 256>(lowb, 16384, lds, O_XA, t);
    stageW16(wsp, lds, O_WB0, t);
    __syncthreads();

    // ---- KV loop: ping-pong weight buffers, 1 barrier/iter ----
    int mt = w & 1, ntq = w >> 1;
    #pragma unroll 1
    for (int qq = 0; qq < 8; ++qq) {
        int cur = O_WB0 + (qq & 1) * 8192;
        int nxt = O_WB0 + ((qq + 1) & 1) * 8192;
        if (qq < 7) stageW16(wsp + (qq + 1) * 8192, lds, nxt, t);
        else        stageW16(wsp + 65536, lds, nxt, t);   // prefetch WQ h0 -> WB0
        f32x4 a = (f32x4){0.f, 0.f, 0.f, 0.f};
        #pragma unroll
        for (int kc = 0; kc < 8; ++kc) {
            short8 af = frag(lds, O_XA, 16 * mt + lm, kc * 32 + lg * 8, 256);
            short8 bf = frag(lds, cur, 16 * ntq + lm, kc * 32 + lg * 8, 256);
            a = __builtin_amdgcn_mfma_f32_16x16x32_bf16(af, bf, a, 0, 0, 0);
        }
        int o = (qq & 3) * 32 + 16 * ntq + lm;
        if (qq < 4) {
            float bb = bk[o];
            #pragma unroll
            for (int r = 0; r < 4; ++r) {
                int tok = 16 * mt + 4 * lg + r;
                lds[O_K + tok * 128 + ((((o >> 1) ^ tok) << 1) | (o & 1))] =
                    (unsigned short)bf16r(a[r] + bb);
            }
        } else {
            float bb = bv[o];
            #pragma unroll
            for (int r = 0; r < 4; ++r) {
                int tok = 16 * mt + 4 * lg + r;
                lds[O_V + tok * 128 + (o ^ ((tok & 7) << 3))] =
                    (unsigned short)bf16r(a[r] + bb);
            }
        }
        __syncthreads();
    }
    // WB0 = WQ h0 (staged during qq=7)

    // ---- pass 1 ----
    float lgr0[2], lgr1[2];
    float sdacc[2] = {0.f, 0.f};

    // dy0: stage XA + WQ h1
    stageA16<64, 128>(hb0, 65536, lds, O_XA, t);
    stageW16(wsp + 65536 + 8192, lds, O_WB1, t);
    __syncthreads();
    {
        f32x4 qA[4], qB[4];
        ZERO4(qA); ZERO4(qB);
        GEMM4(qA, O_WB0);
        GEMM4(qB, O_WB1);
        __syncthreads();                // XA reads done
        QDUMP(qA, 0); QDUMP(qB, 64);
    }
    __syncthreads();                    // Q visible
    ITEMS(lgr0);
    __syncthreads();                    // XA reads done

    // dy1 (WQ halves still resident in WB0/WB1)
    stageA16<64, 128>(hb0 + 256, 65536, lds, O_XA, t);
    __syncthreads();
    {
        f32x4 qA[4], qB[4];
        ZERO4(qA); ZERO4(qB);
        GEMM4(qA, O_WB0);
        GEMM4(qB, O_WB1);
        __syncthreads();
        QDUMP(qA, 0); QDUMP(qB, 64);
    }
    __syncthreads();
    ITEMS(lgr1);
    // overlap: stage WQV halves (WB free since dy1 GEMMs done)
    stageW16(wsp + 81920, lds, O_WB0, t);
    stageW16(wsp + 81920 + 8192, lds, O_WB1, t);
    // write logits + sm
    #pragma unroll
    for (int ii = 0; ii < 2; ++ii) {
        int h = hgrp + 4 * ii;
        lds[O_LG + irow * 8 + (h ^ (irow & 7))]       = (unsigned short)bf16r(lgr0[ii]);
        lds[O_LG + 512 + irow * 8 + (h ^ (irow & 7))] = (unsigned short)bf16r(lgr1[ii]);
        float sdt = sdacc[ii] + __shfl_xor(sdacc[ii], 1, 64);
        if ((t & 1) == 0) smk[(irow >> 1) * 8 + h] = sdt * 0.25f;
    }
    __syncthreads();                    // LG/SM/WQV visible; XA reads (ITEMS) done

    // ---- softmax + re-stage XA(dy0) ----
    stageA16<64, 128>(hb0, 65536, lds, O_XA, t);
    {
        int jj = t >> 3, h = t & 7;
        int ra = 2 * jj, rb2 = 2 * jj + 1;
        int a0 = ra * 8 + (h ^ (ra & 7));
        int a1 = rb2 * 8 + (h ^ (rb2 & 7));
        int a2 = 512 + a0;
        int a3 = 512 + a1;
        float l0 = ubf(lds[O_LG + a0]), l1 = ubf(lds[O_LG + a1]);
        float l2 = ubf(lds[O_LG + a2]), l3 = ubf(lds[O_LG + a3]);
        float mx = fmaxf(fmaxf(l0, l1), fmaxf(l2, l3));
        float e0 = __expf(l0 - mx), e1 = __expf(l1 - mx);
        float e2 = __expf(l2 - mx), e3 = __expf(l3 - mx);
        float inv = 1.f / (e0 + e1 + e2 + e3);
        lds[O_LG + a0] = (unsigned short)bf16r(e0 * inv);
        lds[O_LG + a1] = (unsigned short)bf16r(e1 * inv);
        lds[O_LG + a2] = (unsigned short)bf16r(e2 * inv);
        lds[O_LG + a3] = (unsigned short)bf16r(e3 * inv);
    }
    __syncthreads();

    // ---- pass 2, dy = 0 then 1 ----
    #pragma unroll 1
    for (int dy = 0; dy < 2; ++dy) {
        {
            f32x4 vA[4], vB[4];
            ZERO4(vA); ZERO4(vB);
            GEMM4(vA, O_WB0);
            GEMM4(vB, O_WB1);
            __syncthreads();            // XA reads done
            COMBINE(vA, dy, 0);
            COMBINE(vB, dy, 1);
        }
        // overlap: stage WP halves (WB free)
        stageW16(wsp + 98304, lds, O_WB0, t);
        stageW16(wsp + 98304 + 8192, lds, O_WB1, t);
        __syncthreads();                // xc + WP visible
        {
            f32x4 pA[4], pB[4];
            ZERO4(pA); ZERO4(pB);
            GEMM4(pA, O_WB0);
            GEMM4(pB, O_WB1);
            __syncthreads();            // XA reads done
            LN_YN(pA, pB);
        }
        __syncthreads();                // yn visible
        // store + residual
        {
            const float* rb = hb0 + dy * 256;
            float* ob = out + (size_t)s * 33554432
                      + ((size_t)(b * 128)) * 65536 + (size_t)(2 * i0 + dy) * 256 + 2 * j0;
            int ph = t & 63, cq = t >> 6;
            #pragma unroll
            for (int it2 = 0; it2 < 16; ++it2) {
                int c4 = it2 * 4 + cq;
                unsigned uv = *(const unsigned*)&lds[O_XA + ph * 128 + ((c4 ^ (ph & 31)) << 1)];
                size_t off0 = (size_t)(2 * c4) * 65536 + ph;
                size_t off1 = off0 + 65536;
                ob[off0] = rb[off0] + ulo(uv);
                ob[off1] = rb[off1] + uhi(uv);
            }
        }
        if (dy == 0) {
            __syncthreads();            // yn reads done
            // re-stage XA(dy1) + WQV halves for dy1
            stageA16<64, 128>(hb0 + 256, 65536, lds, O_XA, t);
            stageW16(wsp + 81920, lds, O_WB0, t);
            stageW16(wsp + 81920 + 8192, lds, O_WB1, t);
            __syncthreads();
        }
    }
}

extern "C" void kernel_launch(void* const* d_in, const int* in_sizes, int n_in,
                              void* d_out, int out_size, void* d_ws, size_t ws_size,
                              hipStream_t stream) {
    const float* x_l   = (const float*)d_in[0];
    const float* x_r   = (const float*)d_in[1];
    const float* x_lh  = (const float*)d_in[2];
    const float* x_rh  = (const float*)d_in[3];
    const float* Wq    = (const float*)d_in[4];
    const float* bq    = (const float*)d_in[5];
    const float* Wqv   = (const float*)d_in[6];
    const float* bqv   = (const float*)d_in[7];
    const float* Wk    = (const float*)d_in[8];
    const float* bk    = (const float*)d_in[9];
    const float* Wv    = (const float*)d_in[10];
    const float* bv    = (const float*)d_in[11];
    const float* Wp    = (const float*)d_in[12];
    const float* bp    = (const float*)d_in[13];
    const float* ln_g  = (const float*)d_in[14];
    const float* ln_b  = (const float*)d_in[15];
    const float* dln1g = (const float*)d_in[16];
    const float* dln1b = (const float*)d_in[17];
    const float* d_wsv = (const float*)d_in[18];
    const float* d_w1  = (const float*)d_in[19];
    const float* dln2g = (const float*)d_in[20];
    const float* dln2b = (const float*)d_in[21];
    const float* d_w2  = (const float*)d_in[22];

    float* out = (float*)d_out;
    float* ws_mean = (float*)d_ws;                                 // 2048 f
    float* ws_cm   = ws_mean + 2048;                               // 1024 f
    unsigned short* wsp = (unsigned short*)((char*)d_ws + 16384);  // 224 KB bf16 pool

    mean_kernel<<<2048, 256, 0, stream>>>(x_l, x_r, ws_mean);
    wprep<<<112, 256, 0, stream>>>(Wq, Wqv, Wk, Wv, Wp, wsp);
    cm_kernel<<<8, 128, 0, stream>>>(ws_mean, ws_cm, Wk, bk, d_w1, dln2g, dln2b, d_w2);
    pafm_v12<<<4096, 256, 0, stream>>>(x_l, x_r, x_lh, x_rh,
                                       bq, bqv, bk, bv, bp, ln_g, ln_b,
                                       dln1g, dln1b, d_wsv, ws_cm, wsp, out);
}